// Round 2
// baseline (824.641 us; speedup 1.0000x reference)
//
#include <hip/hip_runtime.h>
#include <hip/hip_bf16.h>
#include <stdint.h>

using bf16 = __hip_bfloat16;
using short8 = __attribute__((ext_vector_type(8))) short;   // 8 bf16 (4 VGPRs)
using f32x4 = __attribute__((ext_vector_type(4))) float;    // 4 fp32 acc

#define T_SEQ 2048
#define DMODEL 1024
#define NHEAD 16
#define DHEAD 64
#define DFF 4096

struct __align__(8) bf16x4 { bf16 x, y, z, w; };

__device__ __forceinline__ void async_cp16(const bf16* g, bf16* l) {
  __builtin_amdgcn_global_load_lds(
      (const __attribute__((address_space(1))) uint32_t*)g,
      (__attribute__((address_space(3))) uint32_t*)l, 16, 0, 0);
}

// ---------------- fused weight transposes + pos cvt: one launch ----------------
// blocks [0,3072): qkvw 1024x3072 -> wqkvT
// blocks [3072,4096): rw 1024x1024 -> wrT
// blocks [4096,5120): ow 1024x1024 -> woT
// blocks [5120,9216): ff1 1024x4096 -> wf1T
// blocks [9216,13312): ff2 4096x1024 -> wf2T
// blocks [13312,15360): pos fp32 -> bf16 elementwise (x4)
__global__ __launch_bounds__(256) void transpose_all(
    const float* __restrict__ s0, bf16* __restrict__ d0,
    const float* __restrict__ s1, bf16* __restrict__ d1,
    const float* __restrict__ s2, bf16* __restrict__ d2,
    const float* __restrict__ s3, bf16* __restrict__ d3,
    const float* __restrict__ s4, bf16* __restrict__ d4,
    const float* __restrict__ s5, bf16* __restrict__ d5) {
  __shared__ float tile[32][33];
  int b = blockIdx.x;
  int tx = threadIdx.x, ty = threadIdx.y;  // 32 x 8
  if (b >= 13312) {  // pos cvt
    int idx = (b - 13312) * 256 + ty * 32 + tx;
    float4 v = ((const float4*)s5)[idx];
    bf16x4 o{__float2bfloat16(v.x), __float2bfloat16(v.y),
             __float2bfloat16(v.z), __float2bfloat16(v.w)};
    ((bf16x4*)d5)[idx] = o;
    return;
  }
  const float* src; bf16* dst; int R, C, t;
  if (b < 3072)      { src = s0; dst = d0; R = 1024; C = 3072; t = b; }
  else if (b < 4096) { src = s1; dst = d1; R = 1024; C = 1024; t = b - 3072; }
  else if (b < 5120) { src = s2; dst = d2; R = 1024; C = 1024; t = b - 4096; }
  else if (b < 9216) { src = s3; dst = d3; R = 1024; C = 4096; t = b - 5120; }
  else               { src = s4; dst = d4; R = 4096; C = 1024; t = b - 9216; }
  int tcols = C >> 5;
  int bx = (t % tcols) * 32;  // col of src
  int by = (t / tcols) * 32;  // row of src
#pragma unroll
  for (int r = 0; r < 32; r += 8)
    tile[ty + r][tx] = src[(long)(by + ty + r) * C + bx + tx];
  __syncthreads();
#pragma unroll
  for (int r = 0; r < 32; r += 8)
    dst[(long)(bx + ty + r) * R + by + tx] = __float2bfloat16(tile[tx][ty + r]);
}

// ---------------- LayerNorm (D=1024) -> bf16, one block per row ----------------
__global__ __launch_bounds__(256) void ln_cvt(const float* __restrict__ x,
                                              const float* __restrict__ g,
                                              const float* __restrict__ b,
                                              bf16* __restrict__ out) {
  int row = blockIdx.x;
  int tid = threadIdx.x;
  float4 v = ((const float4*)(x + (long)row * DMODEL))[tid];
  float s = v.x + v.y + v.z + v.w;
  float s2 = v.x * v.x + v.y * v.y + v.z * v.z + v.w * v.w;
#pragma unroll
  for (int off = 32; off > 0; off >>= 1) {
    s += __shfl_down(s, off);
    s2 += __shfl_down(s2, off);
  }
  __shared__ float ss[4], ss2[4];
  int wave = tid >> 6, lane = tid & 63;
  if (lane == 0) { ss[wave] = s; ss2[wave] = s2; }
  __syncthreads();
  s = ss[0] + ss[1] + ss[2] + ss[3];
  s2 = ss2[0] + ss2[1] + ss2[2] + ss2[3];
  float mean = s * (1.0f / DMODEL);
  float var = s2 * (1.0f / DMODEL) - mean * mean;
  float rstd = rsqrtf(var + 1e-5f);
  float4 gg = ((const float4*)g)[tid];
  float4 bb = ((const float4*)b)[tid];
  bf16x4 o{__float2bfloat16((v.x - mean) * rstd * gg.x + bb.x),
           __float2bfloat16((v.y - mean) * rstd * gg.y + bb.y),
           __float2bfloat16((v.z - mean) * rstd * gg.z + bb.z),
           __float2bfloat16((v.w - mean) * rstd * gg.w + bb.w)};
  ((bf16x4*)(out + (long)row * DMODEL))[tid] = o;
}

// ---------------- generic MFMA GEMM: C(M,N) = A(M,K) * Bt(N,K)^T ----------------
template <int BN, class Epi>
__global__ __launch_bounds__(256) void gemm_bt(const bf16* __restrict__ A,
                                               const bf16* __restrict__ Bt,
                                               int M, int N, int K,
                                               long aZstride, long bZstride, Epi epi) {
  constexpr int BM = 128;
  constexpr int BK = 32;
  constexpr int NT = BN / 32;
  __shared__ bf16 As[BM * BK];
  __shared__ bf16 Bs[BN * BK];

  const int bm = blockIdx.y, bn = blockIdx.x, z = blockIdx.z;
  const bf16* Ab = A + (long)z * aZstride;
  const bf16* Bb = Bt + (long)z * bZstride;

  const int tid = threadIdx.x;
  const int lane = tid & 63;
  const int wave = tid >> 6;
  const int wr = wave >> 1;
  const int wc = wave & 1;
  const int kEnd = epi.kmax(bm, bn, K);

  const f32x4 zero4 = {0.f, 0.f, 0.f, 0.f};
  f32x4 acc[4][NT];
#pragma unroll
  for (int mt = 0; mt < 4; ++mt)
#pragma unroll
    for (int nt = 0; nt < NT; ++nt) acc[mt][nt] = zero4;

  const int sr = tid >> 2;         // staging row within 64-row round
  const int sc = (tid & 3) * 8;    // staging col
  const bf16* aG0 = Ab + (long)(bm * BM + sr) * K + sc;
  const bf16* aG1 = Ab + (long)(bm * BM + 64 + sr) * K + sc;
  bf16* aL0 = As + tid * 8;
  bf16* aL1 = As + 2048 + tid * 8;
  const bf16* bG0 = Bb + (long)(bn * BN + sr) * K + sc;
  bf16* bL0 = Bs + tid * 8;
  const bf16* bG1 = Bb + (long)(bn * BN + 64 + sr) * K + sc;  // BN==128 only
  bf16* bL1 = Bs + 2048 + tid * 8;

  const int aRow = wr * 64 + (lane & 15);
  const int bRow = wc * (BN / 2) + (lane & 15);
  const int kq = (lane >> 4) * 8;

  for (int k0 = 0; k0 < kEnd; k0 += BK) {
    __syncthreads();
    async_cp16(aG0, aL0);
    async_cp16(aG1, aL1);
    async_cp16(bG0, bL0);
    if constexpr (BN == 128) async_cp16(bG1, bL1);
    aG0 += BK; aG1 += BK; bG0 += BK;
    if constexpr (BN == 128) bG1 += BK;
    __syncthreads();
    short8 af[4], bfr[NT];
#pragma unroll
    for (int mt = 0; mt < 4; ++mt)
      af[mt] = *(const short8*)(As + (aRow + mt * 16) * BK + kq);
#pragma unroll
    for (int nt = 0; nt < NT; ++nt)
      bfr[nt] = *(const short8*)(Bs + (bRow + nt * 16) * BK + kq);
#pragma unroll
    for (int mt = 0; mt < 4; ++mt)
#pragma unroll
      for (int nt = 0; nt < NT; ++nt)
        acc[mt][nt] = __builtin_amdgcn_mfma_f32_16x16x32_bf16(af[mt], bfr[nt],
                                                              acc[mt][nt], 0, 0, 0);
  }

  const int rBase = (lane >> 4) * 4;
  const int cOff = lane & 15;
#pragma unroll
  for (int mt = 0; mt < 4; ++mt) {
#pragma unroll
    for (int nt = 0; nt < NT; ++nt) {
      int row = bm * BM + wr * 64 + mt * 16 + rBase;
      int col = bn * BN + wc * (BN / 2) + nt * 16 + cOff;
      f32x4 v = acc[mt][nt];
#pragma unroll
      for (int r = 0; r < 4; ++r) epi.store(z, row + r, col, v[r]);
    }
  }
}

// ---------------- epilogues ----------------
struct EpiQKV {
  bf16 *Qh, *Kb, *Vt;
  __device__ int kmax(int, int, int K) const { return K; }
  __device__ void store(int, int row, int col, float v) const {
    int n = (col >> 6) & 15, d = col & 63;
    long hoff = ((long)n * T_SEQ + row) * DHEAD + d;
    if (col < DMODEL) {
      Qh[hoff] = __float2bfloat16(v);
    } else if (col < 2 * DMODEL) {
      Kb[hoff] = __float2bfloat16(v);
    } else {
      Vt[((long)n * DHEAD + d) * T_SEQ + row] = __float2bfloat16(v);
    }
  }
};

struct EpiRk {
  bf16* Rk;
  __device__ int kmax(int, int, int K) const { return K; }
  __device__ void store(int, int row, int col, float v) const {
    int n = col >> 6, d = col & 63;
    Rk[((long)n * T_SEQ + row) * DHEAD + d] = __float2bfloat16(v);
  }
};

struct EpiPV {
  bf16* av;
  __device__ int kmax(int bm, int, int K) const {
    int kl = (bm + 1) * 128;
    return kl < K ? kl : K;
  }
  __device__ void store(int z, int row, int col, float v) const {
    av[(long)row * DMODEL + z * DHEAD + col] = __float2bfloat16(v);
  }
};

struct EpiO {
  float* xws;
  const float* inp;
  __device__ int kmax(int, int, int K) const { return K; }
  __device__ void store(int, int row, int col, float v) const {
    long idx = (long)row * DMODEL + col;
    xws[idx] = v + inp[idx];
  }
};

struct EpiFF1 {
  bf16* h;
  const float* b1;
  __device__ int kmax(int, int, int K) const { return K; }
  __device__ void store(int, int row, int col, float v) const {
    h[(long)row * DFF + col] = __float2bfloat16(fmaxf(v + b1[col], 0.f));
  }
};

struct EpiFF2 {
  float* out;
  const float* b2;
  const float* xws;
  __device__ int kmax(int, int, int K) const { return K; }
  __device__ void store(int, int row, int col, float v) const {
    long idx = (long)row * DMODEL + col;
    out[idx] = v + b2[col] + xws[idx];
  }
};

// ---------------- rank-1 bias rows: acB[n][j] = rwb_n . K[n][j],  rrbR[n][u] = rrb_n . Rk[n][u]
__global__ __launch_bounds__(256) void bias_k(const bf16* __restrict__ Kb,
                                              const bf16* __restrict__ Rk,
                                              const float* __restrict__ rwb,
                                              const float* __restrict__ rrb,
                                              float* __restrict__ acB,
                                              float* __restrict__ rrbR) {
  int idx = blockIdx.x * 256 + threadIdx.x;   // 16*2048
  int n = idx >> 11;
  const short8* kp = (const short8*)(Kb + (long)idx * DHEAD);
  const short8* rp = (const short8*)(Rk + (long)idx * DHEAD);
  float s1 = 0.f, s2 = 0.f;
#pragma unroll
  for (int q8 = 0; q8 < 8; ++q8) {
    short8 kv = kp[q8], rv = rp[q8];
#pragma unroll
    for (int e = 0; e < 8; ++e) {
      float w1 = rwb[n * DHEAD + q8 * 8 + e];
      float w2 = rrb[n * DHEAD + q8 * 8 + e];
      s1 += w1 * __bfloat162float(((const bf16*)&kv)[e]);
      s2 += w2 * __bfloat162float(((const bf16*)&rv)[e]);
    }
  }
  acB[idx] = s1;
  rrbR[idx] = s2;
}

// ---------------- fused score kernel: score = Q.K^T + rwb-term + relshift(Q.Rk^T) + rrb-term
// Tile (bm,bn) 128x128, head z. BD[i,j] = Q[i].Rk[j-i+2047]; band u = c-r+128,
// g = base+u, base = 128*(bn-bm)+2047-128. W(128x256)=Q.Band^T via MFMA.
// W is only consumed on the parallelogram u in [113-r0, 255-r0] per 16-row block
// (r0 = block's first row): (mt,ut) MFMA/write pairs outside the window are
// pruned. ut blocks are wc-interleaved (ub = (ut*2+wc)*16) so the kept pairs
// balance ~18 per wave (contiguous split was 10/26/26/10). Epilogue folds W into
// accA in place, scatters to a 128x132 LDS tile, then does coalesced short8
// stores (was 64 scalar 2B global stores per lane).
__global__ __launch_bounds__(256) void score_k(const bf16* __restrict__ Qh,
                                               const bf16* __restrict__ Kb,
                                               const bf16* __restrict__ Rk,
                                               const float* __restrict__ acB,
                                               const float* __restrict__ rrbR,
                                               bf16* __restrict__ score) {
  const int bn = blockIdx.x, bm = blockIdx.y, z = blockIdx.z;
  if (bn > bm) return;
  __shared__ char smem[70656];         // staging 64KB | Wl 2x64x276 | Ss 128x132
  bf16* Qs  = (bf16*)smem;             // 128x64, two 32-wide K panels (16 KB)
  bf16* Ks  = (bf16*)(smem + 16384);   // 128x64 (16 KB)
  bf16* Bnd = (bf16*)(smem + 32768);   // 256x64 (32 KB)

  const int tid = threadIdx.x;
  const int lane = tid & 63, wave = tid >> 6;
  const int wr = wave >> 1, wc = wave & 1;
  const int kq = (lane >> 4) * 8;
  const int l15 = lane & 15;
  const int base = 128 * (bn - bm) + T_SEQ - 1 - 128;

  const bf16* Qg = Qh + ((long)z * T_SEQ + bm * 128) * DHEAD;
  const bf16* Kg = Kb + ((long)z * T_SEQ + bn * 128) * DHEAD;
  const bf16* Rg = Rk + (long)z * T_SEQ * DHEAD;

  // stage Q,K (panels: kh*4096 + r*32 + c elements)
#pragma unroll
  for (int it = 0; it < 4; ++it) {
    int s = it * 256 + tid;
    int kh = s >> 9, r = (s >> 2) & 127, c = (s & 3) * 8;
    async_cp16(Qg + (long)r * DHEAD + kh * 32 + c, Qs + s * 8);
    async_cp16(Kg + (long)r * DHEAD + kh * 32 + c, Ks + s * 8);
  }
  // stage Rk band (panels: kh*8192 + u*32 + c elements), clamped rows
#pragma unroll
  for (int it = 0; it < 8; ++it) {
    int s = it * 256 + tid;
    int kh = s >> 10, u = (s >> 2) & 255, c = (s & 3) * 8;
    int g = base + u;
    g = g < 0 ? 0 : (g > T_SEQ - 1 ? T_SEQ - 1 : g);
    async_cp16(Rg + (long)g * DHEAD + kh * 32 + c, Bnd + s * 8);
  }

  // per-(mt,ut) keep masks (wave-uniform); ub = (ut*2+wc)*16 interleave
  int ubs[8];
  bool keepP[4][8];
  bool needUt[8];
#pragma unroll
  for (int ut = 0; ut < 8; ++ut) { ubs[ut] = (ut * 2 + wc) * 16; needUt[ut] = false; }
#pragma unroll
  for (int mt = 0; mt < 4; ++mt) {
    int r0 = wr * 64 + mt * 16;
#pragma unroll
    for (int ut = 0; ut < 8; ++ut) {
      bool k = (ubs[ut] + 15 >= 113 - r0) && (ubs[ut] <= 255 - r0);
      keepP[mt][ut] = k;
      needUt[ut] = needUt[ut] || k;
    }
  }
  const bool diag = (bm == bn);

  const f32x4 zero4 = {0.f, 0.f, 0.f, 0.f};
  f32x4 accA[4][4], accW[4][8];
#pragma unroll
  for (int mt = 0; mt < 4; ++mt) {
#pragma unroll
    for (int nt = 0; nt < 4; ++nt) accA[mt][nt] = zero4;
#pragma unroll
    for (int ut = 0; ut < 8; ++ut) accW[mt][ut] = zero4;
  }

  __syncthreads();
#pragma unroll
  for (int kh = 0; kh < 2; ++kh) {
    short8 qa[4], kf[4], wf[8];
#pragma unroll
    for (int mt = 0; mt < 4; ++mt)
      qa[mt] = *(const short8*)(Qs + kh * 4096 + (wr * 64 + mt * 16 + l15) * 32 + kq);
#pragma unroll
    for (int nt = 0; nt < 4; ++nt)
      kf[nt] = *(const short8*)(Ks + kh * 4096 + (wc * 64 + nt * 16 + l15) * 32 + kq);
#pragma unroll
    for (int ut = 0; ut < 8; ++ut)
      if (needUt[ut])
        wf[ut] = *(const short8*)(Bnd + kh * 8192 + (ubs[ut] + l15) * 32 + kq);
#pragma unroll
    for (int mt = 0; mt < 4; ++mt) {
#pragma unroll
      for (int nt = 0; nt < 4; ++nt)
        if (!(diag && (wc * 64 + nt * 16 > wr * 64 + mt * 16 + 15)))
          accA[mt][nt] = __builtin_amdgcn_mfma_f32_16x16x32_bf16(qa[mt], kf[nt], accA[mt][nt], 0, 0, 0);
#pragma unroll
      for (int ut = 0; ut < 8; ++ut)
        if (keepP[mt][ut])
          accW[mt][ut] = __builtin_amdgcn_mfma_f32_16x16x32_bf16(qa[mt], wf[ut], accW[mt][ut], 0, 0, 0);
    }
  }

  // per-lane bias terms (global, independent of smem) — issue before the barrier
  float wbias[8];
#pragma unroll
  for (int ut = 0; ut < 8; ++ut) {
    int g = base + ubs[ut] + l15;
    g = g < 0 ? 0 : (g > T_SEQ - 1 ? T_SEQ - 1 : g);
    wbias[ut] = rrbR[(long)z * T_SEQ + g];
  }
  float abias[4];
#pragma unroll
  for (int nt = 0; nt < 4; ++nt)
    abias[nt] = acB[(long)z * T_SEQ + bn * 128 + wc * 64 + nt * 16 + l15];

  __syncthreads();  // all frag reads done; smem reusable

  // write kept W blocks into this half's 64x276 region (wc-interleaved u)
  bf16* Wl = (bf16*)smem + wr * (64 * 276);
  const int quad4 = (lane >> 4) * 4;
#pragma unroll
  for (int mt = 0; mt < 4; ++mt) {
#pragma unroll
    for (int ut = 0; ut < 8; ++ut) {
      if (!keepP[mt][ut]) continue;
      int lr = mt * 16 + quad4;
      int u = ubs[ut] + l15;
#pragma unroll
      for (int reg = 0; reg < 4; ++reg)
        Wl[(lr + reg) * 276 + u] = __float2bfloat16(accW[mt][ut][reg] + wbias[ut]);
    }
  }
  __syncthreads();

  // fold W + biases into accA in place
#pragma unroll
  for (int mt = 0; mt < 4; ++mt) {
#pragma unroll
    for (int nt = 0; nt < 4; ++nt) {
      int lr = mt * 16 + quad4;
      int c = wc * 64 + nt * 16 + l15;
#pragma unroll
      for (int reg = 0; reg < 4; ++reg) {
        int rl = lr + reg;
        int u = c - (wr * 64 + rl) + 128;
        accA[mt][nt][reg] += abias[nt] + __bfloat162float(Wl[rl * 276 + u]);
      }
    }
  }
  __syncthreads();  // Wl reads done; reuse smem for score tile

  // scatter to 128x132 score tile (quad rows 4*132 elem apart = 8 banks: no conflict)
  bf16* Ss = (bf16*)smem;
#pragma unroll
  for (int mt = 0; mt < 4; ++mt) {
#pragma unroll
    for (int nt = 0; nt < 4; ++nt) {
      int lr = mt * 16 + quad4;
      int c = wc * 64 + nt * 16 + l15;
#pragma unroll
      for (int reg = 0; reg < 4; ++reg)
        Ss[(wr * 64 + lr + reg) * 132 + c] = __float2bfloat16(accA[mt][nt][reg]);
    }
  }
  __syncthreads();

  // coalesced vector store: 16 threads per row, 16B each
  bf16* srow = score + (long)z * T_SEQ * T_SEQ;
#pragma unroll
  for (int it = 0; it < 8; ++it) {
    int s = it * 256 + tid;
    int row = s >> 4, c8 = (s & 15) * 8;
    *(short8*)(srow + (long)(bm * 128 + row) * T_SEQ + bn * 128 + c8) =
        *(const short8*)(Ss + row * 132 + c8);
  }
}

// ---------------- softmax: block per row i; 16 waves, wave h owns head h ----------------
// Row cached in registers (single global read). 1024 thr + 65.9KB LDS -> 2 blk/CU
// = 32 waves/CU.
__global__ __launch_bounds__(1024) void softmax_k(const bf16* __restrict__ S,
                                                  float* __restrict__ probs,
                                                  bf16* __restrict__ pb) {
  constexpr int HS = T_SEQ + 8;            // LDS head stride (bf16), 16B pad
  __shared__ bf16 pl[NHEAD * HS];          // ~65.8 KB
  __shared__ float rinv_s[NHEAD];
  const int i = blockIdx.x;
  const int tid = threadIdx.x;
  const int h = tid >> 6, lane = tid & 63;
  const float scale = 0.125f;              // 1/sqrt(64)
  const int nch = (i >> 9) + 1;            // 512-wide chunks covering the row

  const bf16* row = S + (long)h * T_SEQ * T_SEQ + (long)i * T_SEQ;

  short8 v[4];
  float m = -1e30f;
#pragma unroll
  for (int c = 0; c < 4; ++c) {
    if (c < nch) {
      int j0 = c * 512 + lane * 8;
      v[c] = *(const short8*)(row + j0);
#pragma unroll
      for (int e = 0; e < 8; ++e) {
        float s = (j0 + e <= i) ? __bfloat162float(((const bf16*)&v[c])[e]) * scale : -1e30f;
        m = fmaxf(m, s);
      }
    }
  }
#pragma unroll
  for (int off = 1; off < 64; off <<= 1) m = fmaxf(m, __shfl_xor(m, off));

  float l = 0.f;
#pragma unroll
  for (int c = 0; c < 4; ++c) {
    if (c < nch) {
      int j0 = c * 512 + lane * 8;
      short8 o;
#pragma unroll
      for (int e = 0; e < 8; ++e) {
        float p = 0.f;
        if (j0 + e <= i) {
          p = __expf(__bfloat162float(((const bf16*)&v[c])[e]) * scale - m);
          l += p;
        }
        ((bf16*)&o)[e] = __float2bfloat16(p);
      }
      *(short8*)(pl + h * HS + j0) = o;
    }
  }
#pragma unroll
  for (int off = 1; off < 64; off <<= 1) l += __shfl_xor(l, off);
  if (lane == 0) rinv_s[h] = 1.f / l;
  __syncthreads();

  // probs fp32 [i][j][n] — float4 coalesced via LDS transpose (all 1024 threads)
  float* prow = probs + (long)i * T_SEQ * NHEAD;
  const int n0 = (tid & 3) * 4;
  const float rv0 = rinv_s[n0 + 0], rv1 = rinv_s[n0 + 1];
  const float rv2 = rinv_s[n0 + 2], rv3 = rinv_s[n0 + 3];
#pragma unroll
  for (int it = 0; it < 8; ++it) {
    int o = it * 1024 + tid;
    int j = o >> 2;
    float4 f = {0.f, 0.f, 0.f, 0.f};
    if (j <= i) {
      f.x = __bfloat162float(pl[(n0 + 0) * HS + j]) * rv0;
      f.y = __bfloat162float(pl[(n0 + 1) * HS + j]) * rv1;
      f.z = __bfloat162float(pl[(n0 + 2) * HS + j]) * rv2;
      f.w = __bfloat162float(pl[(n0 + 3) * HS + j]) * rv3;
    }
    ((float4*)prow)[o] = f;
  }

  // pb bf16 [n][i][j], normalized, j < round_up(i+1,128); wave h writes head h
  const int kround = ((i >> 7) + 1) << 7;
  bf16* prow_b = pb + (long)h * T_SEQ * T_SEQ + (long)i * T_SEQ;
  const float rinv = rinv_s[h];
  for (int j0 = lane * 8; j0 < kround; j0 += 512) {
    short8 pv = *(const short8*)(pl + h * HS + j0);
    short8 o;
#pragma unroll
    for (int e = 0; e < 8; ++e)
      ((bf16*)&o)[e] = __float2bfloat16(__bfloat162float(((const bf16*)&pv)[e]) * rinv);
    *(short8*)(prow_b + j0) = o;
  }
}

// ---------------- host launch ----------------
extern "C" void kernel_launch(void* const* d_in, const int* in_sizes, int n_in,
                              void* d_out, int out_size, void* d_ws, size_t ws_size,
                              hipStream_t stream) {
  const float* input = (const float*)d_in[0];
  const float* pos   = (const float*)d_in[1];
  const float* rwb   = (const float*)d_in[2];
  const float* rrb   = (const float*)d_in[3];
  // d_in[4] = mask (causal, recomputed analytically)
  const float* ln1g  = (const float*)d_in[5];
  const float* ln1b  = (const float*)d_in[6];
  const float* qkvw  = (const float*)d_in[7];
  const float* rw    = (const float*)d_in[8];
  const float* ow    = (const float*)d_in[9];
  const float* ln2g  = (const float*)d_in[10];
  const float* ln2b  = (const float*)d_in[11];
  const float* ffw1  = (const float*)d_in[12];
  const float* ffb1  = (const float*)d_in[13];
  const float* ffw2  = (const float*)d_in[14];
  const float* ffb2  = (const float*)d_in[15];
  float* out = (float*)d_out;  // [0, 2M): x   [2M, 2M+67M): probs

  size_t off = 0;
  auto alloc = [&](size_t bytes) -> char* {
    char* p = (char*)d_ws + off;
    off += (bytes + 255) & ~(size_t)255;
    return p;
  };
  bf16* wqkvT = (bf16*)alloc(3072L * 1024 * 2);
  bf16* wrT   = (bf16*)alloc(1024L * 1024 * 2);
  bf16* woT   = (bf16*)alloc(1024L * 1024 * 2);
  bf16* wf1T  = (bf16*)alloc(4096L * 1024 * 2);
  bf16* wf2T  = (bf16*)alloc(1024L * 4096 * 2);
  bf16* qin   = (bf16*)alloc(2048L * 1024 * 2);
  bf16* posb  = (bf16*)alloc(2048L * 1024 * 2);
  bf16* Qh    = (bf16*)alloc(16L * 2048 * 64 * 2);
  bf16* Kb    = (bf16*)alloc(16L * 2048 * 64 * 2);
  bf16* Vt    = (bf16*)alloc(16L * 64 * 2048 * 2);
  bf16* Rk    = (bf16*)alloc(16L * 2048 * 64 * 2);
  float* acB  = (float*)alloc(16L * 2048 * 4);
  float* rrbR = (float*)alloc(16L * 2048 * 4);
  bf16* ACb   = (bf16*)alloc(16L * 2048 * 2048 * 2);  // 134 MB score
  bf16* pb    = (bf16*)alloc(16L * 2048 * 2048 * 2);  // 134 MB probs bf16
  bf16* av    = (bf16*)alloc(2048L * 1024 * 2);
  float* xws  = (float*)alloc(2048L * 1024 * 4);
  bf16* yb    = (bf16*)alloc(2048L * 1024 * 2);
  bf16* hb    = (bf16*)alloc(2048L * 4096 * 2);

  dim3 tb(32, 8);
  transpose_all<<<15360, tb, 0, stream>>>(qkvw, wqkvT, rw, wrT, ow, woT,
                                          ffw1, wf1T, ffw2, wf2T, pos, posb);
  ln_cvt<<<2048, 256, 0, stream>>>(input, ln1g, ln1b, qin);

  {
    EpiQKV e{Qh, Kb, Vt};
    gemm_bt<128, EpiQKV><<<dim3(24, 16, 1), 256, 0, stream>>>(qin, wqkvT, 2048, 3072, 1024, 0, 0, e);
  }
  {
    EpiRk e{Rk};
    gemm_bt<64, EpiRk><<<dim3(16, 16, 1), 256, 0, stream>>>(posb, wrT, 2048, 1024, 1024, 0, 0, e);
  }
  bias_k<<<128, 256, 0, stream>>>(Kb, Rk, rwb, rrb, acB, rrbR);
  score_k<<<dim3(16, 16, 16), 256, 0, stream>>>(Qh, Kb, Rk, acB, rrbR, ACb);
  softmax_k<<<2048, 1024, 0, stream>>>(ACb, out + 2048L * 1024, pb);
  {
    EpiPV e{av};
    gemm_bt<64, EpiPV><<<dim3(1, 16, 16), 256, 0, stream>>>(pb, Vt, 2048, 64, 2048,
                                                            2048L * 2048, 64L * 2048, e);
  }
  {
    EpiO e{xws, input};
    gemm_bt<64, EpiO><<<dim3(16, 16, 1), 256, 0, stream>>>(av, woT, 2048, 1024, 1024, 0, 0, e);
  }
  ln_cvt<<<2048, 256, 0, stream>>>(xws, ln2g, ln2b, yb);
  {
    EpiFF1 e{hb, ffb1};
    gemm_bt<128, EpiFF1><<<dim3(32, 16, 1), 256, 0, stream>>>(yb, wf1T, 2048, 4096, 1024, 0, 0, e);
  }
  {
    EpiFF2 e{out, ffb2, xws};
    gemm_bt<64, EpiFF2><<<dim3(16, 16, 1), 256, 0, stream>>>(hb, wf2T, 2048, 1024, 4096, 0, 0, e);
  }
}

// Round 3
// 733.163 us; speedup vs baseline: 1.1248x; 1.1248x over previous
//
#include <hip/hip_runtime.h>
#include <hip/hip_bf16.h>
#include <stdint.h>

using bf16 = __hip_bfloat16;
using short8 = __attribute__((ext_vector_type(8))) short;   // 8 bf16 (4 VGPRs)
using f32x4 = __attribute__((ext_vector_type(4))) float;    // 4 fp32 acc

#define T_SEQ 2048
#define DMODEL 1024
#define NHEAD 16
#define DHEAD 64
#define DFF 4096

struct __align__(8) bf16x4 { bf16 x, y, z, w; };

__device__ __forceinline__ void async_cp16(const bf16* g, bf16* l) {
  __builtin_amdgcn_global_load_lds(
      (const __attribute__((address_space(1))) uint32_t*)g,
      (__attribute__((address_space(3))) uint32_t*)l, 16, 0, 0);
}

// ---------------- fused weight transposes + pos cvt: one launch ----------------
__global__ __launch_bounds__(256) void transpose_all(
    const float* __restrict__ s0, bf16* __restrict__ d0,
    const float* __restrict__ s1, bf16* __restrict__ d1,
    const float* __restrict__ s2, bf16* __restrict__ d2,
    const float* __restrict__ s3, bf16* __restrict__ d3,
    const float* __restrict__ s4, bf16* __restrict__ d4,
    const float* __restrict__ s5, bf16* __restrict__ d5) {
  __shared__ float tile[32][33];
  int b = blockIdx.x;
  int tx = threadIdx.x, ty = threadIdx.y;  // 32 x 8
  if (b >= 13312) {  // pos cvt
    int idx = (b - 13312) * 256 + ty * 32 + tx;
    float4 v = ((const float4*)s5)[idx];
    bf16x4 o{__float2bfloat16(v.x), __float2bfloat16(v.y),
             __float2bfloat16(v.z), __float2bfloat16(v.w)};
    ((bf16x4*)d5)[idx] = o;
    return;
  }
  const float* src; bf16* dst; int R, C, t;
  if (b < 3072)      { src = s0; dst = d0; R = 1024; C = 3072; t = b; }
  else if (b < 4096) { src = s1; dst = d1; R = 1024; C = 1024; t = b - 3072; }
  else if (b < 5120) { src = s2; dst = d2; R = 1024; C = 1024; t = b - 4096; }
  else if (b < 9216) { src = s3; dst = d3; R = 1024; C = 4096; t = b - 5120; }
  else               { src = s4; dst = d4; R = 4096; C = 1024; t = b - 9216; }
  int tcols = C >> 5;
  int bx = (t % tcols) * 32;  // col of src
  int by = (t / tcols) * 32;  // row of src
#pragma unroll
  for (int r = 0; r < 32; r += 8)
    tile[ty + r][tx] = src[(long)(by + ty + r) * C + bx + tx];
  __syncthreads();
#pragma unroll
  for (int r = 0; r < 32; r += 8)
    dst[(long)(bx + ty + r) * R + by + tx] = __float2bfloat16(tile[tx][ty + r]);
}

// ---------------- LayerNorm (D=1024) -> bf16, one block per row ----------------
__global__ __launch_bounds__(256) void ln_cvt(const float* __restrict__ x,
                                              const float* __restrict__ g,
                                              const float* __restrict__ b,
                                              bf16* __restrict__ out) {
  int row = blockIdx.x;
  int tid = threadIdx.x;
  float4 v = ((const float4*)(x + (long)row * DMODEL))[tid];
  float s = v.x + v.y + v.z + v.w;
  float s2 = v.x * v.x + v.y * v.y + v.z * v.z + v.w * v.w;
#pragma unroll
  for (int off = 32; off > 0; off >>= 1) {
    s += __shfl_down(s, off);
    s2 += __shfl_down(s2, off);
  }
  __shared__ float ss[4], ss2[4];
  int wave = tid >> 6, lane = tid & 63;
  if (lane == 0) { ss[wave] = s; ss2[wave] = s2; }
  __syncthreads();
  s = ss[0] + ss[1] + ss[2] + ss[3];
  s2 = ss2[0] + ss2[1] + ss2[2] + ss2[3];
  float mean = s * (1.0f / DMODEL);
  float var = s2 * (1.0f / DMODEL) - mean * mean;
  float rstd = rsqrtf(var + 1e-5f);
  float4 gg = ((const float4*)g)[tid];
  float4 bb = ((const float4*)b)[tid];
  bf16x4 o{__float2bfloat16((v.x - mean) * rstd * gg.x + bb.x),
           __float2bfloat16((v.y - mean) * rstd * gg.y + bb.y),
           __float2bfloat16((v.z - mean) * rstd * gg.z + bb.z),
           __float2bfloat16((v.w - mean) * rstd * gg.w + bb.w)};
  ((bf16x4*)(out + (long)row * DMODEL))[tid] = o;
}

// ---------------- fp32 out = b2 + xws (pre-init for split-K FF2 atomics) ----------------
__global__ __launch_bounds__(256) void ff2_init(const float* __restrict__ xws,
                                                const float* __restrict__ b2,
                                                float* __restrict__ out) {
  int idx = blockIdx.x * 256 + threadIdx.x;   // float4 index over 2048*1024
  float4 x = ((const float4*)xws)[idx];
  float4 b = ((const float4*)b2)[idx & 255];
  float4 o{x.x + b.x, x.y + b.y, x.z + b.z, x.w + b.w};
  ((float4*)out)[idx] = o;
}

// ---------------- generic MFMA GEMM: C(M,N) = A(M,K) * Bt(N,K)^T ----------------
// BM,BN in {64,128}; 4 waves as 2x2. kmin/kmax hooks enable causal limits and split-K.
template <int BM, int BN, class Epi>
__global__ __launch_bounds__(256) void gemm_bt(const bf16* __restrict__ A,
                                               const bf16* __restrict__ Bt,
                                               int M, int N, int K,
                                               long aZstride, long bZstride, Epi epi) {
  constexpr int BK = 32;
  constexpr int MT = BM / 32;
  constexpr int NT = BN / 32;
  __shared__ bf16 As[BM * BK];
  __shared__ bf16 Bs[BN * BK];

  const int bm = blockIdx.y, bn = blockIdx.x, z = blockIdx.z;
  const bf16* Ab = A + (long)z * aZstride;
  const bf16* Bb = Bt + (long)z * bZstride;

  const int tid = threadIdx.x;
  const int lane = tid & 63;
  const int wave = tid >> 6;
  const int wr = wave >> 1;
  const int wc = wave & 1;
  const int kBeg = epi.kmin(bm, bn, z);
  const int kEnd = epi.kmax(bm, bn, z, K);

  const f32x4 zero4 = {0.f, 0.f, 0.f, 0.f};
  f32x4 acc[MT][NT];
#pragma unroll
  for (int mt = 0; mt < MT; ++mt)
#pragma unroll
    for (int nt = 0; nt < NT; ++nt) acc[mt][nt] = zero4;

  const int sr = tid >> 2;         // staging row within 64-row round
  const int sc = (tid & 3) * 8;    // staging col
  const bf16* aG0 = Ab + (long)(bm * BM + sr) * K + kBeg + sc;
  const bf16* aG1 = Ab + (long)(bm * BM + 64 + sr) * K + kBeg + sc;  // BM==128
  bf16* aL0 = As + tid * 8;
  bf16* aL1 = As + 2048 + tid * 8;
  const bf16* bG0 = Bb + (long)(bn * BN + sr) * K + kBeg + sc;
  bf16* bL0 = Bs + tid * 8;
  const bf16* bG1 = Bb + (long)(bn * BN + 64 + sr) * K + kBeg + sc;  // BN==128
  bf16* bL1 = Bs + 2048 + tid * 8;

  const int aRow = wr * (BM / 2) + (lane & 15);
  const int bRow = wc * (BN / 2) + (lane & 15);
  const int kq = (lane >> 4) * 8;

  for (int k0 = kBeg; k0 < kEnd; k0 += BK) {
    __syncthreads();
    async_cp16(aG0, aL0);
    if constexpr (BM == 128) async_cp16(aG1, aL1);
    async_cp16(bG0, bL0);
    if constexpr (BN == 128) async_cp16(bG1, bL1);
    aG0 += BK; bG0 += BK;
    if constexpr (BM == 128) aG1 += BK;
    if constexpr (BN == 128) bG1 += BK;
    __syncthreads();
    short8 af[MT], bfr[NT];
#pragma unroll
    for (int mt = 0; mt < MT; ++mt)
      af[mt] = *(const short8*)(As + (aRow + mt * 16) * BK + kq);
#pragma unroll
    for (int nt = 0; nt < NT; ++nt)
      bfr[nt] = *(const short8*)(Bs + (bRow + nt * 16) * BK + kq);
#pragma unroll
    for (int mt = 0; mt < MT; ++mt)
#pragma unroll
      for (int nt = 0; nt < NT; ++nt)
        acc[mt][nt] = __builtin_amdgcn_mfma_f32_16x16x32_bf16(af[mt], bfr[nt],
                                                              acc[mt][nt], 0, 0, 0);
  }

  const int rBase = (lane >> 4) * 4;
  const int cOff = lane & 15;
#pragma unroll
  for (int mt = 0; mt < MT; ++mt) {
#pragma unroll
    for (int nt = 0; nt < NT; ++nt) {
      int row = bm * BM + wr * (BM / 2) + mt * 16 + rBase;
      int col = bn * BN + wc * (BN / 2) + nt * 16 + cOff;
      f32x4 v = acc[mt][nt];
#pragma unroll
      for (int r = 0; r < 4; ++r) epi.store(z, row + r, col, v[r]);
    }
  }
}

// ---------------- epilogues ----------------
struct EpiQKV {
  bf16 *Qh, *Kb, *Vt;
  __device__ int kmin(int, int, int) const { return 0; }
  __device__ int kmax(int, int, int, int K) const { return K; }
  __device__ void store(int, int row, int col, float v) const {
    int n = (col >> 6) & 15, d = col & 63;
    long hoff = ((long)n * T_SEQ + row) * DHEAD + d;
    if (col < DMODEL) {
      Qh[hoff] = __float2bfloat16(v);
    } else if (col < 2 * DMODEL) {
      Kb[hoff] = __float2bfloat16(v);
    } else {
      Vt[((long)n * DHEAD + d) * T_SEQ + row] = __float2bfloat16(v);
    }
  }
};

struct EpiRk {
  bf16* Rk;
  __device__ int kmin(int, int, int) const { return 0; }
  __device__ int kmax(int, int, int, int K) const { return K; }
  __device__ void store(int, int row, int col, float v) const {
    int n = col >> 6, d = col & 63;
    Rk[((long)n * T_SEQ + row) * DHEAD + d] = __float2bfloat16(v);
  }
};

// PV with BM=64: rows [bm*64, bm*64+64) all share kround = ((bm>>1)+1)*128
struct EpiPV {
  bf16* av;
  __device__ int kmin(int, int, int) const { return 0; }
  __device__ int kmax(int bm, int, int, int K) const {
    int kl = ((bm >> 1) + 1) * 128;
    return kl < K ? kl : K;
  }
  __device__ void store(int z, int row, int col, float v) const {
    av[(long)row * DMODEL + z * DHEAD + col] = __float2bfloat16(v);
  }
};

struct EpiO {
  float* xws;
  const float* inp;
  __device__ int kmin(int, int, int) const { return 0; }
  __device__ int kmax(int, int, int, int K) const { return K; }
  __device__ void store(int, int row, int col, float v) const {
    long idx = (long)row * DMODEL + col;
    xws[idx] = v + inp[idx];
  }
};

struct EpiFF1 {
  bf16* h;
  const float* b1;
  __device__ int kmin(int, int, int) const { return 0; }
  __device__ int kmax(int, int, int, int K) const { return K; }
  __device__ void store(int, int row, int col, float v) const {
    h[(long)row * DFF + col] = __float2bfloat16(fmaxf(v + b1[col], 0.f));
  }
};

// split-K x4: out pre-initialized with b2+xws; partials atomic-added (fp32 HW atomic)
struct EpiFF2 {
  float* out;
  __device__ int kmin(int, int, int z) const { return z * 1024; }
  __device__ int kmax(int, int, int z, int K) const {
    int e = z * 1024 + 1024;
    return e < K ? e : K;
  }
  __device__ void store(int, int row, int col, float v) const {
    unsafeAtomicAdd(&out[(long)row * DMODEL + col], v);
  }
};

// ---------------- rank-1 bias rows ----------------
__global__ __launch_bounds__(256) void bias_k(const bf16* __restrict__ Kb,
                                              const bf16* __restrict__ Rk,
                                              const float* __restrict__ rwb,
                                              const float* __restrict__ rrb,
                                              float* __restrict__ acB,
                                              float* __restrict__ rrbR) {
  int idx = blockIdx.x * 256 + threadIdx.x;   // 16*2048
  int n = idx >> 11;
  const short8* kp = (const short8*)(Kb + (long)idx * DHEAD);
  const short8* rp = (const short8*)(Rk + (long)idx * DHEAD);
  float s1 = 0.f, s2 = 0.f;
#pragma unroll
  for (int q8 = 0; q8 < 8; ++q8) {
    short8 kv = kp[q8], rv = rp[q8];
#pragma unroll
    for (int e = 0; e < 8; ++e) {
      float w1 = rwb[n * DHEAD + q8 * 8 + e];
      float w2 = rrb[n * DHEAD + q8 * 8 + e];
      s1 += w1 * __bfloat162float(((const bf16*)&kv)[e]);
      s2 += w2 * __bfloat162float(((const bf16*)&rv)[e]);
    }
  }
  acB[idx] = s1;
  rrbR[idx] = s2;
}

// ---------------- fused score kernel (round-1 version, verbatim) ----------------
__global__ __launch_bounds__(256) void score_k(const bf16* __restrict__ Qh,
                                               const bf16* __restrict__ Kb,
                                               const bf16* __restrict__ Rk,
                                               const float* __restrict__ acB,
                                               const float* __restrict__ rrbR,
                                               bf16* __restrict__ score) {
  const int bn = blockIdx.x, bm = blockIdx.y, z = blockIdx.z;
  if (bn > bm) return;
  __shared__ char smem[70656];               // max(staging 64KB, 2*64*276*2)
  bf16* Qs  = (bf16*)smem;             // 128x64, two 32-wide K panels (16 KB)
  bf16* Ks  = (bf16*)(smem + 16384);   // 128x64 (16 KB)
  bf16* Bnd = (bf16*)(smem + 32768);   // 256x64 (32 KB)

  const int tid = threadIdx.x;
  const int lane = tid & 63, wave = tid >> 6;
  const int wr = wave >> 1, wc = wave & 1;
  const int kq = (lane >> 4) * 8;
  const int l15 = lane & 15;
  const int base = 128 * (bn - bm) + T_SEQ - 1 - 128;

  const bf16* Qg = Qh + ((long)z * T_SEQ + bm * 128) * DHEAD;
  const bf16* Kg = Kb + ((long)z * T_SEQ + bn * 128) * DHEAD;
  const bf16* Rg = Rk + (long)z * T_SEQ * DHEAD;

#pragma unroll
  for (int it = 0; it < 4; ++it) {
    int s = it * 256 + tid;
    int kh = s >> 9, r = (s >> 2) & 127, c = (s & 3) * 8;
    async_cp16(Qg + (long)r * DHEAD + kh * 32 + c, Qs + s * 8);
    async_cp16(Kg + (long)r * DHEAD + kh * 32 + c, Ks + s * 8);
  }
#pragma unroll
  for (int it = 0; it < 8; ++it) {
    int s = it * 256 + tid;
    int kh = s >> 10, u = (s >> 2) & 255, c = (s & 3) * 8;
    int g = base + u;
    g = g < 0 ? 0 : (g > T_SEQ - 1 ? T_SEQ - 1 : g);
    async_cp16(Rg + (long)g * DHEAD + kh * 32 + c, Bnd + s * 8);
  }

  const f32x4 zero4 = {0.f, 0.f, 0.f, 0.f};
  f32x4 accA[4][4], accW[4][8];
#pragma unroll
  for (int mt = 0; mt < 4; ++mt) {
#pragma unroll
    for (int nt = 0; nt < 4; ++nt) accA[mt][nt] = zero4;
#pragma unroll
    for (int ut = 0; ut < 8; ++ut) accW[mt][ut] = zero4;
  }

  __syncthreads();
#pragma unroll
  for (int kh = 0; kh < 2; ++kh) {
    short8 qa[4], kf[4], wf[8];
#pragma unroll
    for (int mt = 0; mt < 4; ++mt)
      qa[mt] = *(const short8*)(Qs + kh * 4096 + (wr * 64 + mt * 16 + l15) * 32 + kq);
#pragma unroll
    for (int nt = 0; nt < 4; ++nt)
      kf[nt] = *(const short8*)(Ks + kh * 4096 + (wc * 64 + nt * 16 + l15) * 32 + kq);
#pragma unroll
    for (int ut = 0; ut < 8; ++ut)
      wf[ut] = *(const short8*)(Bnd + kh * 8192 + (wc * 128 + ut * 16 + l15) * 32 + kq);
#pragma unroll
    for (int mt = 0; mt < 4; ++mt) {
#pragma unroll
      for (int nt = 0; nt < 4; ++nt)
        accA[mt][nt] = __builtin_amdgcn_mfma_f32_16x16x32_bf16(qa[mt], kf[nt], accA[mt][nt], 0, 0, 0);
#pragma unroll
      for (int ut = 0; ut < 8; ++ut)
        accW[mt][ut] = __builtin_amdgcn_mfma_f32_16x16x32_bf16(qa[mt], wf[ut], accW[mt][ut], 0, 0, 0);
    }
  }

  float wbias[8];
#pragma unroll
  for (int ut = 0; ut < 8; ++ut) {
    int u = wc * 128 + ut * 16 + l15;
    int g = base + u;
    g = g < 0 ? 0 : (g > T_SEQ - 1 ? T_SEQ - 1 : g);
    wbias[ut] = rrbR[(long)z * T_SEQ + g];
  }
  float abias[4];
#pragma unroll
  for (int nt = 0; nt < 4; ++nt)
    abias[nt] = acB[(long)z * T_SEQ + bn * 128 + wc * 64 + nt * 16 + l15];

  __syncthreads();  // all frag reads done; smem reusable

  bf16* Wl = (bf16*)smem + wr * (64 * 276);
  const int quad4 = (lane >> 4) * 4;
  const int umin = wr ? 1 : 65;    // u range actually read back for this half
  const int umax = wr ? 191 : 255;
#pragma unroll
  for (int mt = 0; mt < 4; ++mt) {
#pragma unroll
    for (int ut = 0; ut < 8; ++ut) {
      int ub = wc * 128 + ut * 16;
      if (ub + 15 < umin || ub > umax) continue;
      int lr = mt * 16 + quad4;
      int u = ub + l15;
#pragma unroll
      for (int reg = 0; reg < 4; ++reg)
        Wl[(lr + reg) * 276 + u] = __float2bfloat16(accW[mt][ut][reg] + wbias[ut]);
    }
  }
  __syncthreads();

  bf16* srow = score + (long)z * T_SEQ * T_SEQ;
#pragma unroll
  for (int mt = 0; mt < 4; ++mt) {
#pragma unroll
    for (int nt = 0; nt < 4; ++nt) {
      int lr = mt * 16 + quad4;
      int c = wc * 64 + nt * 16 + l15;
#pragma unroll
      for (int reg = 0; reg < 4; ++reg) {
        int rl = lr + reg;
        int r = wr * 64 + rl;
        int u = c - r + 128;
        float v = accA[mt][nt][reg] + abias[nt] +
                  __bfloat162float(Wl[rl * 276 + u]);
        srow[(long)(bm * 128 + r) * T_SEQ + bn * 128 + c] = __float2bfloat16(v);
      }
    }
  }
}

// ---------------- softmax: block per row i; 16 waves, wave h owns head h ----------------
__global__ __launch_bounds__(1024) void softmax_k(const bf16* __restrict__ S,
                                                  float* __restrict__ probs,
                                                  bf16* __restrict__ pb) {
  constexpr int HS = T_SEQ + 8;            // LDS head stride (bf16), 16B pad
  __shared__ bf16 pl[NHEAD * HS];          // ~65.8 KB
  __shared__ float rinv_s[NHEAD];
  const int i = blockIdx.x;
  const int tid = threadIdx.x;
  const int h = tid >> 6, lane = tid & 63;
  const float scale = 0.125f;              // 1/sqrt(64)
  const int nch = (i >> 9) + 1;            // 512-wide chunks covering the row

  const bf16* row = S + (long)h * T_SEQ * T_SEQ + (long)i * T_SEQ;

  short8 v[4];
  float m = -1e30f;
#pragma unroll
  for (int c = 0; c < 4; ++c) {
    if (c < nch) {
      int j0 = c * 512 + lane * 8;
      v[c] = *(const short8*)(row + j0);
#pragma unroll
      for (int e = 0; e < 8; ++e) {
        float s = (j0 + e <= i) ? __bfloat162float(((const bf16*)&v[c])[e]) * scale : -1e30f;
        m = fmaxf(m, s);
      }
    }
  }
#pragma unroll
  for (int off = 1; off < 64; off <<= 1) m = fmaxf(m, __shfl_xor(m, off));

  float l = 0.f;
#pragma unroll
  for (int c = 0; c < 4; ++c) {
    if (c < nch) {
      int j0 = c * 512 + lane * 8;
      short8 o;
#pragma unroll
      for (int e = 0; e < 8; ++e) {
        float p = 0.f;
        if (j0 + e <= i) {
          p = __expf(__bfloat162float(((const bf16*)&v[c])[e]) * scale - m);
          l += p;
        }
        ((bf16*)&o)[e] = __float2bfloat16(p);
      }
      *(short8*)(pl + h * HS + j0) = o;
    }
  }
#pragma unroll
  for (int off = 1; off < 64; off <<= 1) l += __shfl_xor(l, off);
  if (lane == 0) rinv_s[h] = 1.f / l;
  __syncthreads();

  float* prow = probs + (long)i * T_SEQ * NHEAD;
  const int n0 = (tid & 3) * 4;
  const float rv0 = rinv_s[n0 + 0], rv1 = rinv_s[n0 + 1];
  const float rv2 = rinv_s[n0 + 2], rv3 = rinv_s[n0 + 3];
#pragma unroll
  for (int it = 0; it < 8; ++it) {
    int o = it * 1024 + tid;
    int j = o >> 2;
    float4 f = {0.f, 0.f, 0.f, 0.f};
    if (j <= i) {
      f.x = __bfloat162float(pl[(n0 + 0) * HS + j]) * rv0;
      f.y = __bfloat162float(pl[(n0 + 1) * HS + j]) * rv1;
      f.z = __bfloat162float(pl[(n0 + 2) * HS + j]) * rv2;
      f.w = __bfloat162float(pl[(n0 + 3) * HS + j]) * rv3;
    }
    ((float4*)prow)[o] = f;
  }

  const int kround = ((i >> 7) + 1) << 7;
  bf16* prow_b = pb + (long)h * T_SEQ * T_SEQ + (long)i * T_SEQ;
  const float rinv = rinv_s[h];
  for (int j0 = lane * 8; j0 < kround; j0 += 512) {
    short8 pv = *(const short8*)(pl + h * HS + j0);
    short8 o;
#pragma unroll
    for (int e = 0; e < 8; ++e)
      ((bf16*)&o)[e] = __float2bfloat16(__bfloat162float(((const bf16*)&pv)[e]) * rinv);
    *(short8*)(prow_b + j0) = o;
  }
}

// ---------------- host launch ----------------
extern "C" void kernel_launch(void* const* d_in, const int* in_sizes, int n_in,
                              void* d_out, int out_size, void* d_ws, size_t ws_size,
                              hipStream_t stream) {
  const float* input = (const float*)d_in[0];
  const float* pos   = (const float*)d_in[1];
  const float* rwb   = (const float*)d_in[2];
  const float* rrb   = (const float*)d_in[3];
  // d_in[4] = mask (causal, recomputed analytically)
  const float* ln1g  = (const float*)d_in[5];
  const float* ln1b  = (const float*)d_in[6];
  const float* qkvw  = (const float*)d_in[7];
  const float* rw    = (const float*)d_in[8];
  const float* ow    = (const float*)d_in[9];
  const float* ln2g  = (const float*)d_in[10];
  const float* ln2b  = (const float*)d_in[11];
  const float* ffw1  = (const float*)d_in[12];
  const float* ffb1  = (const float*)d_in[13];
  const float* ffw2  = (const float*)d_in[14];
  const float* ffb2  = (const float*)d_in[15];
  float* out = (float*)d_out;  // [0, 2M): x   [2M, 2M+67M): probs

  size_t off = 0;
  auto alloc = [&](size_t bytes) -> char* {
    char* p = (char*)d_ws + off;
    off += (bytes + 255) & ~(size_t)255;
    return p;
  };
  bf16* wqkvT = (bf16*)alloc(3072L * 1024 * 2);
  bf16* wrT   = (bf16*)alloc(1024L * 1024 * 2);
  bf16* woT   = (bf16*)alloc(1024L * 1024 * 2);
  bf16* wf1T  = (bf16*)alloc(4096L * 1024 * 2);
  bf16* wf2T  = (bf16*)alloc(1024L * 4096 * 2);
  bf16* qin   = (bf16*)alloc(2048L * 1024 * 2);
  bf16* posb  = (bf16*)alloc(2048L * 1024 * 2);
  bf16* Qh    = (bf16*)alloc(16L * 2048 * 64 * 2);
  bf16* Kb    = (bf16*)alloc(16L * 2048 * 64 * 2);
  bf16* Vt    = (bf16*)alloc(16L * 64 * 2048 * 2);
  bf16* Rk    = (bf16*)alloc(16L * 2048 * 64 * 2);
  float* acB  = (float*)alloc(16L * 2048 * 4);
  float* rrbR = (float*)alloc(16L * 2048 * 4);
  bf16* ACb   = (bf16*)alloc(16L * 2048 * 2048 * 2);  // 134 MB score
  bf16* pb    = (bf16*)alloc(16L * 2048 * 2048 * 2);  // 134 MB probs bf16
  bf16* av    = (bf16*)alloc(2048L * 1024 * 2);
  float* xws  = (float*)alloc(2048L * 1024 * 4);
  bf16* yb    = (bf16*)alloc(2048L * 1024 * 2);
  bf16* hb    = (bf16*)alloc(2048L * 4096 * 2);

  dim3 tb(32, 8);
  transpose_all<<<15360, tb, 0, stream>>>(qkvw, wqkvT, rw, wrT, ow, woT,
                                          ffw1, wf1T, ffw2, wf2T, pos, posb);
  ln_cvt<<<2048, 256, 0, stream>>>(input, ln1g, ln1b, qin);

  {
    EpiQKV e{Qh, Kb, Vt};
    gemm_bt<128, 128, EpiQKV><<<dim3(24, 16, 1), 256, 0, stream>>>(qin, wqkvT, 2048, 3072, 1024, 0, 0, e);
  }
  {
    EpiRk e{Rk};
    gemm_bt<64, 64, EpiRk><<<dim3(16, 32, 1), 256, 0, stream>>>(posb, wrT, 2048, 1024, 1024, 0, 0, e);
  }
  bias_k<<<128, 256, 0, stream>>>(Kb, Rk, rwb, rrb, acB, rrbR);
  score_k<<<dim3(16, 16, 16), 256, 0, stream>>>(Qh, Kb, Rk, acB, rrbR, ACb);
  softmax_k<<<2048, 1024, 0, stream>>>(ACb, out + 2048L * 1024, pb);
  {
    EpiPV e{av};
    gemm_bt<64, 64, EpiPV><<<dim3(1, 32, 16), 256, 0, stream>>>(pb, Vt, 2048, 64, 2048,
                                                                2048L * 2048, 64L * 2048, e);
  }
  {
    EpiO e{xws, input};
    gemm_bt<64, 64, EpiO><<<dim3(16, 32, 1), 256, 0, stream>>>(av, woT, 2048, 1024, 1024, 0, 0, e);
  }
  ff2_init<<<2048, 256, 0, stream>>>(xws, ffb2, out);
  ln_cvt<<<2048, 256, 0, stream>>>(xws, ln2g, ln2b, yb);
  {
    EpiFF1 e{hb, ffb1};
    gemm_bt<128, 128, EpiFF1><<<dim3(32, 16, 1), 256, 0, stream>>>(yb, wf1T, 2048, 4096, 1024, 0, 0, e);
  }
  {
    EpiFF2 e{out};
    gemm_bt<128, 64, EpiFF2><<<dim3(16, 16, 4), 256, 0, stream>>>(hb, wf2T, 2048, 1024, 4096, 0, 0, e);
  }
}

// Round 4
// 724.873 us; speedup vs baseline: 1.1376x; 1.0114x over previous
//
#include <hip/hip_runtime.h>
#include <hip/hip_bf16.h>
#include <stdint.h>

using bf16 = __hip_bfloat16;
using short8 = __attribute__((ext_vector_type(8))) short;   // 8 bf16 (4 VGPRs)
using f32x4 = __attribute__((ext_vector_type(4))) float;    // 4 fp32 acc

#define T_SEQ 2048
#define DMODEL 1024
#define NHEAD 16
#define DHEAD 64
#define DFF 4096

struct __align__(8) bf16x4 { bf16 x, y, z, w; };

__device__ __forceinline__ void async_cp16(const bf16* g, bf16* l) {
  __builtin_amdgcn_global_load_lds(
      (const __attribute__((address_space(1))) uint32_t*)g,
      (__attribute__((address_space(3))) uint32_t*)l, 16, 0, 0);
}

// Stage a ROWS x BK bf16 tile (row stride ldg) into LDS in K-paneled layout:
// elem offset = kk*(ROWS*32) + row*32 + (col&31), kk = col>>5.
// LDS destination is linear in thread id (wave-uniform base + lane*16 — required
// by global_load_lds); the panel decomposition is folded into the SOURCE address.
template <int ROWS, int BK>
__device__ __forceinline__ void stage_tile(const bf16* __restrict__ g, int ldg,
                                           bf16* l, int tid) {
  constexpr int PAN = ROWS * 32;            // elems per K-panel
  constexpr int ROUNDS = ROWS * BK / 2048;  // 256 thr x 8 elems per round
#pragma unroll
  for (int r = 0; r < ROUNDS; ++r) {
    int off = (r * 256 + tid) * 8;
    int kkp = off / PAN;
    int rem = off % PAN;
    int row = rem >> 5;
    int col = kkp * 32 + (rem & 31);
    async_cp16(g + (long)row * ldg + col, l + off);
  }
}

// ---------------- fused weight transposes + pos cvt: one launch ----------------
__global__ __launch_bounds__(256) void transpose_all(
    const float* __restrict__ s0, bf16* __restrict__ d0,
    const float* __restrict__ s1, bf16* __restrict__ d1,
    const float* __restrict__ s2, bf16* __restrict__ d2,
    const float* __restrict__ s3, bf16* __restrict__ d3,
    const float* __restrict__ s4, bf16* __restrict__ d4,
    const float* __restrict__ s5, bf16* __restrict__ d5) {
  __shared__ float tile[32][33];
  int b = blockIdx.x;
  int tx = threadIdx.x, ty = threadIdx.y;  // 32 x 8
  if (b >= 13312) {  // pos cvt
    int idx = (b - 13312) * 256 + ty * 32 + tx;
    float4 v = ((const float4*)s5)[idx];
    bf16x4 o{__float2bfloat16(v.x), __float2bfloat16(v.y),
             __float2bfloat16(v.z), __float2bfloat16(v.w)};
    ((bf16x4*)d5)[idx] = o;
    return;
  }
  const float* src; bf16* dst; int R, C, t;
  if (b < 3072)      { src = s0; dst = d0; R = 1024; C = 3072; t = b; }
  else if (b < 4096) { src = s1; dst = d1; R = 1024; C = 1024; t = b - 3072; }
  else if (b < 5120) { src = s2; dst = d2; R = 1024; C = 1024; t = b - 4096; }
  else if (b < 9216) { src = s3; dst = d3; R = 1024; C = 4096; t = b - 5120; }
  else               { src = s4; dst = d4; R = 4096; C = 1024; t = b - 9216; }
  int tcols = C >> 5;
  int bx = (t % tcols) * 32;  // col of src
  int by = (t / tcols) * 32;  // row of src
#pragma unroll
  for (int r = 0; r < 32; r += 8)
    tile[ty + r][tx] = src[(long)(by + ty + r) * C + bx + tx];
  __syncthreads();
#pragma unroll
  for (int r = 0; r < 32; r += 8)
    dst[(long)(bx + ty + r) * R + by + tx] = __float2bfloat16(tile[tx][ty + r]);
}

// ---------------- LayerNorm (D=1024) -> bf16, one block per row ----------------
__global__ __launch_bounds__(256) void ln_cvt(const float* __restrict__ x,
                                              const float* __restrict__ g,
                                              const float* __restrict__ b,
                                              bf16* __restrict__ out) {
  int row = blockIdx.x;
  int tid = threadIdx.x;
  float4 v = ((const float4*)(x + (long)row * DMODEL))[tid];
  float s = v.x + v.y + v.z + v.w;
  float s2 = v.x * v.x + v.y * v.y + v.z * v.z + v.w * v.w;
#pragma unroll
  for (int off = 32; off > 0; off >>= 1) {
    s += __shfl_down(s, off);
    s2 += __shfl_down(s2, off);
  }
  __shared__ float ss[4], ss2[4];
  int wave = tid >> 6, lane = tid & 63;
  if (lane == 0) { ss[wave] = s; ss2[wave] = s2; }
  __syncthreads();
  s = ss[0] + ss[1] + ss[2] + ss[3];
  s2 = ss2[0] + ss2[1] + ss2[2] + ss2[3];
  float mean = s * (1.0f / DMODEL);
  float var = s2 * (1.0f / DMODEL) - mean * mean;
  float rstd = rsqrtf(var + 1e-5f);
  float4 gg = ((const float4*)g)[tid];
  float4 bb = ((const float4*)b)[tid];
  bf16x4 o{__float2bfloat16((v.x - mean) * rstd * gg.x + bb.x),
           __float2bfloat16((v.y - mean) * rstd * gg.y + bb.y),
           __float2bfloat16((v.z - mean) * rstd * gg.z + bb.z),
           __float2bfloat16((v.w - mean) * rstd * gg.w + bb.w)};
  ((bf16x4*)(out + (long)row * DMODEL))[tid] = o;
}

// ---------------- fp32 out = b2 + xws (pre-init for split-K FF2 atomics) ----------------
__global__ __launch_bounds__(256) void ff2_init(const float* __restrict__ xws,
                                                const float* __restrict__ b2,
                                                float* __restrict__ out) {
  int idx = blockIdx.x * 256 + threadIdx.x;   // float4 index over 2048*1024
  float4 x = ((const float4*)xws)[idx];
  float4 b = ((const float4*)b2)[idx & 255];
  float4 o{x.x + b.x, x.y + b.y, x.z + b.z, x.w + b.w};
  ((float4*)out)[idx] = o;
}

// ---------------- generic MFMA GEMM: C(M,N) = A(M,K) * Bt(N,K)^T ----------------
// 2-phase double-buffered pipeline: per K-step {issue STAGE(next) ->
// ds_read(cur)+MFMA -> one __syncthreads (drains this wave's loads + barrier)}.
// Staging latency overlaps the MFMA cluster; 1 barrier per step (was 2).
template <int BM, int BN, int BK, class Epi>
__global__ __launch_bounds__(256) void gemm_bt(const bf16* __restrict__ A,
                                               const bf16* __restrict__ Bt,
                                               int M, int N, int K,
                                               long aZstride, long bZstride, Epi epi) {
  constexpr int MT = BM / 32;
  constexpr int NT = BN / 32;
  constexpr int KK = BK / 32;
  __shared__ bf16 As[2][BM * BK];
  __shared__ bf16 Bs[2][BN * BK];

  const int bm = blockIdx.y, bn = blockIdx.x, z = blockIdx.z;
  const bf16* Ab = A + (long)z * aZstride + (long)bm * BM * K;
  const bf16* Bb = Bt + (long)z * bZstride + (long)bn * BN * K;

  const int tid = threadIdx.x;
  const int lane = tid & 63;
  const int wave = tid >> 6;
  const int wr = wave >> 1;
  const int wc = wave & 1;
  const int kBeg = epi.kmin(bm, bn, z);
  const int kEnd = epi.kmax(bm, bn, z, K);

  const f32x4 zero4 = {0.f, 0.f, 0.f, 0.f};
  f32x4 acc[MT][NT];
#pragma unroll
  for (int mt = 0; mt < MT; ++mt)
#pragma unroll
    for (int nt = 0; nt < NT; ++nt) acc[mt][nt] = zero4;

  const int aRow = wr * (BM / 2) + (lane & 15);
  const int bRow = wc * (BN / 2) + (lane & 15);
  const int kq = (lane >> 4) * 8;

  // prologue: fill buffer 0
  stage_tile<BM, BK>(Ab + kBeg, K, As[0], tid);
  stage_tile<BN, BK>(Bb + kBeg, K, Bs[0], tid);
  __syncthreads();

  int cur = 0;
  for (int k0 = kBeg; k0 < kEnd; k0 += BK) {
    int kn = k0 + BK;
    if (kn < kEnd) {  // issue next-tile loads; they drain at this step's barrier
      stage_tile<BM, BK>(Ab + kn, K, As[cur ^ 1], tid);
      stage_tile<BN, BK>(Bb + kn, K, Bs[cur ^ 1], tid);
    }
    short8 af[KK][MT], bfr[KK][NT];
#pragma unroll
    for (int kk = 0; kk < KK; ++kk) {
#pragma unroll
      for (int mt = 0; mt < MT; ++mt)
        af[kk][mt] = *(const short8*)(&As[cur][kk * (BM * 32) + (aRow + mt * 16) * 32 + kq]);
#pragma unroll
      for (int nt = 0; nt < NT; ++nt)
        bfr[kk][nt] = *(const short8*)(&Bs[cur][kk * (BN * 32) + (bRow + nt * 16) * 32 + kq]);
    }
#pragma unroll
    for (int kk = 0; kk < KK; ++kk)
#pragma unroll
      for (int mt = 0; mt < MT; ++mt)
#pragma unroll
        for (int nt = 0; nt < NT; ++nt)
          acc[mt][nt] = __builtin_amdgcn_mfma_f32_16x16x32_bf16(af[kk][mt], bfr[kk][nt],
                                                                acc[mt][nt], 0, 0, 0);
    __syncthreads();
    cur ^= 1;
  }

  const int rBase = (lane >> 4) * 4;
  const int cOff = lane & 15;
#pragma unroll
  for (int mt = 0; mt < MT; ++mt) {
#pragma unroll
    for (int nt = 0; nt < NT; ++nt) {
      int row = bm * BM + wr * (BM / 2) + mt * 16 + rBase;
      int col = bn * BN + wc * (BN / 2) + nt * 16 + cOff;
      f32x4 v = acc[mt][nt];
#pragma unroll
      for (int r = 0; r < 4; ++r) epi.store(z, row + r, col, v[r]);
    }
  }
}

// ---------------- epilogues ----------------
struct EpiQKV {
  bf16 *Qh, *Kb, *Vt;
  __device__ int kmin(int, int, int) const { return 0; }
  __device__ int kmax(int, int, int, int K) const { return K; }
  __device__ void store(int, int row, int col, float v) const {
    int n = (col >> 6) & 15, d = col & 63;
    long hoff = ((long)n * T_SEQ + row) * DHEAD + d;
    if (col < DMODEL) {
      Qh[hoff] = __float2bfloat16(v);
    } else if (col < 2 * DMODEL) {
      Kb[hoff] = __float2bfloat16(v);
    } else {
      Vt[((long)n * DHEAD + d) * T_SEQ + row] = __float2bfloat16(v);
    }
  }
};

struct EpiRk {
  bf16* Rk;
  __device__ int kmin(int, int, int) const { return 0; }
  __device__ int kmax(int, int, int, int K) const { return K; }
  __device__ void store(int, int row, int col, float v) const {
    int n = col >> 6, d = col & 63;
    Rk[((long)n * T_SEQ + row) * DHEAD + d] = __float2bfloat16(v);
  }
};

// PV with BM=64: rows [bm*64, bm*64+64) all share kround = ((bm>>1)+1)*128
struct EpiPV {
  bf16* av;
  __device__ int kmin(int, int, int) const { return 0; }
  __device__ int kmax(int bm, int, int, int K) const {
    int kl = ((bm >> 1) + 1) * 128;
    return kl < K ? kl : K;
  }
  __device__ void store(int z, int row, int col, float v) const {
    av[(long)row * DMODEL + z * DHEAD + col] = __float2bfloat16(v);
  }
};

struct EpiO {
  float* xws;
  const float* inp;
  __device__ int kmin(int, int, int) const { return 0; }
  __device__ int kmax(int, int, int, int K) const { return K; }
  __device__ void store(int, int row, int col, float v) const {
    long idx = (long)row * DMODEL + col;
    xws[idx] = v + inp[idx];
  }
};

struct EpiFF1 {
  bf16* h;
  const float* b1;
  __device__ int kmin(int, int, int) const { return 0; }
  __device__ int kmax(int, int, int, int K) const { return K; }
  __device__ void store(int, int row, int col, float v) const {
    h[(long)row * DFF + col] = __float2bfloat16(fmaxf(v + b1[col], 0.f));
  }
};

// split-K x4: out pre-initialized with b2+xws; partials atomic-added (fp32 HW atomic)
struct EpiFF2 {
  float* out;
  __device__ int kmin(int, int, int z) const { return z * 1024; }
  __device__ int kmax(int, int, int z, int K) const {
    int e = z * 1024 + 1024;
    return e < K ? e : K;
  }
  __device__ void store(int, int row, int col, float v) const {
    unsafeAtomicAdd(&out[(long)row * DMODEL + col], v);
  }
};

// ---------------- rank-1 bias rows ----------------
__global__ __launch_bounds__(256) void bias_k(const bf16* __restrict__ Kb,
                                              const bf16* __restrict__ Rk,
                                              const float* __restrict__ rwb,
                                              const float* __restrict__ rrb,
                                              float* __restrict__ acB,
                                              float* __restrict__ rrbR) {
  int idx = blockIdx.x * 256 + threadIdx.x;   // 16*2048
  int n = idx >> 11;
  const short8* kp = (const short8*)(Kb + (long)idx * DHEAD);
  const short8* rp = (const short8*)(Rk + (long)idx * DHEAD);
  float s1 = 0.f, s2 = 0.f;
#pragma unroll
  for (int q8 = 0; q8 < 8; ++q8) {
    short8 kv = kp[q8], rv = rp[q8];
#pragma unroll
    for (int e = 0; e < 8; ++e) {
      float w1 = rwb[n * DHEAD + q8 * 8 + e];
      float w2 = rrb[n * DHEAD + q8 * 8 + e];
      s1 += w1 * __bfloat162float(((const bf16*)&kv)[e]);
      s2 += w2 * __bfloat162float(((const bf16*)&rv)[e]);
    }
  }
  acB[idx] = s1;
  rrbR[idx] = s2;
}

// ---------------- fused score kernel (round-1 version, verbatim) ----------------
__global__ __launch_bounds__(256) void score_k(const bf16* __restrict__ Qh,
                                               const bf16* __restrict__ Kb,
                                               const bf16* __restrict__ Rk,
                                               const float* __restrict__ acB,
                                               const float* __restrict__ rrbR,
                                               bf16* __restrict__ score) {
  const int bn = blockIdx.x, bm = blockIdx.y, z = blockIdx.z;
  if (bn > bm) return;
  __shared__ char smem[70656];               // max(staging 64KB, 2*64*276*2)
  bf16* Qs  = (bf16*)smem;             // 128x64, two 32-wide K panels (16 KB)
  bf16* Ks  = (bf16*)(smem + 16384);   // 128x64 (16 KB)
  bf16* Bnd = (bf16*)(smem + 32768);   // 256x64 (32 KB)

  const int tid = threadIdx.x;
  const int lane = tid & 63, wave = tid >> 6;
  const int wr = wave >> 1, wc = wave & 1;
  const int kq = (lane >> 4) * 8;
  const int l15 = lane & 15;
  const int base = 128 * (bn - bm) + T_SEQ - 1 - 128;

  const bf16* Qg = Qh + ((long)z * T_SEQ + bm * 128) * DHEAD;
  const bf16* Kg = Kb + ((long)z * T_SEQ + bn * 128) * DHEAD;
  const bf16* Rg = Rk + (long)z * T_SEQ * DHEAD;

#pragma unroll
  for (int it = 0; it < 4; ++it) {
    int s = it * 256 + tid;
    int kh = s >> 9, r = (s >> 2) & 127, c = (s & 3) * 8;
    async_cp16(Qg + (long)r * DHEAD + kh * 32 + c, Qs + s * 8);
    async_cp16(Kg + (long)r * DHEAD + kh * 32 + c, Ks + s * 8);
  }
#pragma unroll
  for (int it = 0; it < 8; ++it) {
    int s = it * 256 + tid;
    int kh = s >> 10, u = (s >> 2) & 255, c = (s & 3) * 8;
    int g = base + u;
    g = g < 0 ? 0 : (g > T_SEQ - 1 ? T_SEQ - 1 : g);
    async_cp16(Rg + (long)g * DHEAD + kh * 32 + c, Bnd + s * 8);
  }

  const f32x4 zero4 = {0.f, 0.f, 0.f, 0.f};
  f32x4 accA[4][4], accW[4][8];
#pragma unroll
  for (int mt = 0; mt < 4; ++mt) {
#pragma unroll
    for (int nt = 0; nt < 4; ++nt) accA[mt][nt] = zero4;
#pragma unroll
    for (int ut = 0; ut < 8; ++ut) accW[mt][ut] = zero4;
  }

  __syncthreads();
#pragma unroll
  for (int kh = 0; kh < 2; ++kh) {
    short8 qa[4], kf[4], wf[8];
#pragma unroll
    for (int mt = 0; mt < 4; ++mt)
      qa[mt] = *(const short8*)(Qs + kh * 4096 + (wr * 64 + mt * 16 + l15) * 32 + kq);
#pragma unroll
    for (int nt = 0; nt < 4; ++nt)
      kf[nt] = *(const short8*)(Ks + kh * 4096 + (wc * 64 + nt * 16 + l15) * 32 + kq);
#pragma unroll
    for (int ut = 0; ut < 8; ++ut)
      wf[ut] = *(const short8*)(Bnd + kh * 8192 + (wc * 128 + ut * 16 + l15) * 32 + kq);
#pragma unroll
    for (int mt = 0; mt < 4; ++mt) {
#pragma unroll
      for (int nt = 0; nt < 4; ++nt)
        accA[mt][nt] = __builtin_amdgcn_mfma_f32_16x16x32_bf16(qa[mt], kf[nt], accA[mt][nt], 0, 0, 0);
#pragma unroll
      for (int ut = 0; ut < 8; ++ut)
        accW[mt][ut] = __builtin_amdgcn_mfma_f32_16x16x32_bf16(qa[mt], wf[ut], accW[mt][ut], 0, 0, 0);
    }
  }

  float wbias[8];
#pragma unroll
  for (int ut = 0; ut < 8; ++ut) {
    int u = wc * 128 + ut * 16 + l15;
    int g = base + u;
    g = g < 0 ? 0 : (g > T_SEQ - 1 ? T_SEQ - 1 : g);
    wbias[ut] = rrbR[(long)z * T_SEQ + g];
  }
  float abias[4];
#pragma unroll
  for (int nt = 0; nt < 4; ++nt)
    abias[nt] = acB[(long)z * T_SEQ + bn * 128 + wc * 64 + nt * 16 + l15];

  __syncthreads();  // all frag reads done; smem reusable

  bf16* Wl = (bf16*)smem + wr * (64 * 276);
  const int quad4 = (lane >> 4) * 4;
  const int umin = wr ? 1 : 65;    // u range actually read back for this half
  const int umax = wr ? 191 : 255;
#pragma unroll
  for (int mt = 0; mt < 4; ++mt) {
#pragma unroll
    for (int ut = 0; ut < 8; ++ut) {
      int ub = wc * 128 + ut * 16;
      if (ub + 15 < umin || ub > umax) continue;
      int lr = mt * 16 + quad4;
      int u = ub + l15;
#pragma unroll
      for (int reg = 0; reg < 4; ++reg)
        Wl[(lr + reg) * 276 + u] = __float2bfloat16(accW[mt][ut][reg] + wbias[ut]);
    }
  }
  __syncthreads();

  bf16* srow = score + (long)z * T_SEQ * T_SEQ;
#pragma unroll
  for (int mt = 0; mt < 4; ++mt) {
#pragma unroll
    for (int nt = 0; nt < 4; ++nt) {
      int lr = mt * 16 + quad4;
      int c = wc * 64 + nt * 16 + l15;
#pragma unroll
      for (int reg = 0; reg < 4; ++reg) {
        int rl = lr + reg;
        int r = wr * 64 + rl;
        int u = c - r + 128;
        float v = accA[mt][nt][reg] + abias[nt] +
                  __bfloat162float(Wl[rl * 276 + u]);
        srow[(long)(bm * 128 + r) * T_SEQ + bn * 128 + c] = __float2bfloat16(v);
      }
    }
  }
}

// ---------------- softmax: block per row i; 16 waves, wave h owns head h ----------------
__global__ __launch_bounds__(1024) void softmax_k(const bf16* __restrict__ S,
                                                  float* __restrict__ probs,
                                                  bf16* __restrict__ pb) {
  constexpr int HS = T_SEQ + 8;            // LDS head stride (bf16), 16B pad
  __shared__ bf16 pl[NHEAD * HS];          // ~65.8 KB
  __shared__ float rinv_s[NHEAD];
  const int i = blockIdx.x;
  const int tid = threadIdx.x;
  const int h = tid >> 6, lane = tid & 63;
  const float scale = 0.125f;              // 1/sqrt(64)
  const int nch = (i >> 9) + 1;            // 512-wide chunks covering the row

  const bf16* row = S + (long)h * T_SEQ * T_SEQ + (long)i * T_SEQ;

  short8 v[4];
  float m = -1e30f;
#pragma unroll
  for (int c = 0; c < 4; ++c) {
    if (c < nch) {
      int j0 = c * 512 + lane * 8;
      v[c] = *(const short8*)(row + j0);
#pragma unroll
      for (int e = 0; e < 8; ++e) {
        float s = (j0 + e <= i) ? __bfloat162float(((const bf16*)&v[c])[e]) * scale : -1e30f;
        m = fmaxf(m, s);
      }
    }
  }
#pragma unroll
  for (int off = 1; off < 64; off <<= 1) m = fmaxf(m, __shfl_xor(m, off));

  float l = 0.f;
#pragma unroll
  for (int c = 0; c < 4; ++c) {
    if (c < nch) {
      int j0 = c * 512 + lane * 8;
      short8 o;
#pragma unroll
      for (int e = 0; e < 8; ++e) {
        float p = 0.f;
        if (j0 + e <= i) {
          p = __expf(__bfloat162float(((const bf16*)&v[c])[e]) * scale - m);
          l += p;
        }
        ((bf16*)&o)[e] = __float2bfloat16(p);
      }
      *(short8*)(pl + h * HS + j0) = o;
    }
  }
#pragma unroll
  for (int off = 1; off < 64; off <<= 1) l += __shfl_xor(l, off);
  if (lane == 0) rinv_s[h] = 1.f / l;
  __syncthreads();

  float* prow = probs + (long)i * T_SEQ * NHEAD;
  const int n0 = (tid & 3) * 4;
  const float rv0 = rinv_s[n0 + 0], rv1 = rinv_s[n0 + 1];
  const float rv2 = rinv_s[n0 + 2], rv3 = rinv_s[n0 + 3];
#pragma unroll
  for (int it = 0; it < 8; ++it) {
    int o = it * 1024 + tid;
    int j = o >> 2;
    float4 f = {0.f, 0.f, 0.f, 0.f};
    if (j <= i) {
      f.x = __bfloat162float(pl[(n0 + 0) * HS + j]) * rv0;
      f.y = __bfloat162float(pl[(n0 + 1) * HS + j]) * rv1;
      f.z = __bfloat162float(pl[(n0 + 2) * HS + j]) * rv2;
      f.w = __bfloat162float(pl[(n0 + 3) * HS + j]) * rv3;
    }
    ((float4*)prow)[o] = f;
  }

  const int kround = ((i >> 7) + 1) << 7;
  bf16* prow_b = pb + (long)h * T_SEQ * T_SEQ + (long)i * T_SEQ;
  const float rinv = rinv_s[h];
  for (int j0 = lane * 8; j0 < kround; j0 += 512) {
    short8 pv = *(const short8*)(pl + h * HS + j0);
    short8 o;
#pragma unroll
    for (int e = 0; e < 8; ++e)
      ((bf16*)&o)[e] = __float2bfloat16(__bfloat162float(((const bf16*)&pv)[e]) * rinv);
    *(short8*)(prow_b + j0) = o;
  }
}

// ---------------- host launch ----------------
extern "C" void kernel_launch(void* const* d_in, const int* in_sizes, int n_in,
                              void* d_out, int out_size, void* d_ws, size_t ws_size,
                              hipStream_t stream) {
  const float* input = (const float*)d_in[0];
  const float* pos   = (const float*)d_in[1];
  const float* rwb   = (const float*)d_in[2];
  const float* rrb   = (const float*)d_in[3];
  // d_in[4] = mask (causal, recomputed analytically)
  const float* ln1g  = (const float*)d_in[5];
  const float* ln1b  = (const float*)d_in[6];
  const float* qkvw  = (const float*)d_in[7];
  const float* rw    = (const float*)d_in[8];
  const float* ow    = (const float*)d_in[9];
  const float* ln2g  = (const float*)d_in[10];
  const float* ln2b  = (const float*)d_in[11];
  const float* ffw1  = (const float*)d_in[12];
  const float* ffb1  = (const float*)d_in[13];
  const float* ffw2  = (const float*)d_in[14];
  const float* ffb2  = (const float*)d_in[15];
  float* out = (float*)d_out;  // [0, 2M): x   [2M, 2M+67M): probs

  size_t off = 0;
  auto alloc = [&](size_t bytes) -> char* {
    char* p = (char*)d_ws + off;
    off += (bytes + 255) & ~(size_t)255;
    return p;
  };
  bf16* wqkvT = (bf16*)alloc(3072L * 1024 * 2);
  bf16* wrT   = (bf16*)alloc(1024L * 1024 * 2);
  bf16* woT   = (bf16*)alloc(1024L * 1024 * 2);
  bf16* wf1T  = (bf16*)alloc(4096L * 1024 * 2);
  bf16* wf2T  = (bf16*)alloc(1024L * 4096 * 2);
  bf16* qin   = (bf16*)alloc(2048L * 1024 * 2);
  bf16* posb  = (bf16*)alloc(2048L * 1024 * 2);
  bf16* Qh    = (bf16*)alloc(16L * 2048 * 64 * 2);
  bf16* Kb    = (bf16*)alloc(16L * 2048 * 64 * 2);
  bf16* Vt    = (bf16*)alloc(16L * 64 * 2048 * 2);
  bf16* Rk    = (bf16*)alloc(16L * 2048 * 64 * 2);
  float* acB  = (float*)alloc(16L * 2048 * 4);
  float* rrbR = (float*)alloc(16L * 2048 * 4);
  bf16* ACb   = (bf16*)alloc(16L * 2048 * 2048 * 2);  // 134 MB score
  bf16* pb    = (bf16*)alloc(16L * 2048 * 2048 * 2);  // 134 MB probs bf16
  bf16* av    = (bf16*)alloc(2048L * 1024 * 2);
  float* xws  = (float*)alloc(2048L * 1024 * 4);
  bf16* yb    = (bf16*)alloc(2048L * 1024 * 2);
  bf16* hb    = (bf16*)alloc(2048L * 4096 * 2);

  dim3 tb(32, 8);
  transpose_all<<<15360, tb, 0, stream>>>(qkvw, wqkvT, rw, wrT, ow, woT,
                                          ffw1, wf1T, ffw2, wf2T, pos, posb);
  ln_cvt<<<2048, 256, 0, stream>>>(input, ln1g, ln1b, qin);

  {
    EpiQKV e{Qh, Kb, Vt};
    gemm_bt<128, 128, 32, EpiQKV><<<dim3(24, 16, 1), 256, 0, stream>>>(qin, wqkvT, 2048, 3072, 1024, 0, 0, e);
  }
  {
    EpiRk e{Rk};
    gemm_bt<64, 64, 64, EpiRk><<<dim3(16, 32, 1), 256, 0, stream>>>(posb, wrT, 2048, 1024, 1024, 0, 0, e);
  }
  bias_k<<<128, 256, 0, stream>>>(Kb, Rk, rwb, rrb, acB, rrbR);
  score_k<<<dim3(16, 16, 16), 256, 0, stream>>>(Qh, Kb, Rk, acB, rrbR, ACb);
  softmax_k<<<2048, 1024, 0, stream>>>(ACb, out + 2048L * 1024, pb);
  {
    EpiPV e{av};
    gemm_bt<64, 64, 64, EpiPV><<<dim3(1, 32, 16), 256, 0, stream>>>(pb, Vt, 2048, 64, 2048,
                                                                    2048L * 2048, 64L * 2048, e);
  }
  {
    EpiO e{xws, input};
    gemm_bt<64, 64, 64, EpiO><<<dim3(16, 32, 1), 256, 0, stream>>>(av, woT, 2048, 1024, 1024, 0, 0, e);
  }
  ff2_init<<<2048, 256, 0, stream>>>(xws, ffb2, out);
  ln_cvt<<<2048, 256, 0, stream>>>(xws, ln2g, ln2b, yb);
  {
    EpiFF1 e{hb, ffb1};
    gemm_bt<128, 128, 32, EpiFF1><<<dim3(32, 16, 1), 256, 0, stream>>>(yb, wf1T, 2048, 4096, 1024, 0, 0, e);
  }
  {
    EpiFF2 e{out};
    gemm_bt<128, 64, 64, EpiFF2><<<dim3(16, 16, 4), 256, 0, stream>>>(hb, wf2T, 2048, 1024, 4096, 0, 0, e);
  }
}

// Round 5
// 720.745 us; speedup vs baseline: 1.1442x; 1.0057x over previous
//
#include <hip/hip_runtime.h>
#include <hip/hip_bf16.h>
#include <stdint.h>

using bf16 = __hip_bfloat16;
using short8 = __attribute__((ext_vector_type(8))) short;   // 8 bf16 (4 VGPRs)
using f32x4 = __attribute__((ext_vector_type(4))) float;    // 4 fp32 acc

#define T_SEQ 2048
#define DMODEL 1024
#define NHEAD 16
#define DHEAD 64
#define DFF 4096

struct __align__(8) bf16x4 { bf16 x, y, z, w; };

__device__ __forceinline__ void async_cp16(const bf16* g, bf16* l) {
  __builtin_amdgcn_global_load_lds(
      (const __attribute__((address_space(1))) uint32_t*)g,
      (__attribute__((address_space(3))) uint32_t*)l, 16, 0, 0);
}

// Stage a ROWS x BK bf16 tile (row stride ldg) into LDS in K-paneled layout:
// elem offset = kk*(ROWS*32) + row*32 + (col&31), kk = col>>5.
// LDS destination is linear in thread id (wave-uniform base + lane*16 — required
// by global_load_lds); the panel decomposition is folded into the SOURCE address.
template <int ROWS, int BK>
__device__ __forceinline__ void stage_tile(const bf16* __restrict__ g, int ldg,
                                           bf16* l, int tid) {
  constexpr int PAN = ROWS * 32;            // elems per K-panel
  constexpr int ROUNDS = ROWS * BK / 2048;  // 256 thr x 8 elems per round
#pragma unroll
  for (int r = 0; r < ROUNDS; ++r) {
    int off = (r * 256 + tid) * 8;
    int kkp = off / PAN;
    int rem = off % PAN;
    int row = rem >> 5;
    int col = kkp * 32 + (rem & 31);
    async_cp16(g + (long)row * ldg + col, l + off);
  }
}

// ---------------- fused: weight transposes + pos cvt + LN1 : one launch ----------------
// blocks [0,13312): five weight transposes
// blocks [13312,15360): pos fp32 -> bf16 (x4)
// blocks [15360,17408): LayerNorm rows of input -> qin (bf16)
__global__ __launch_bounds__(256) void transpose_all(
    const float* __restrict__ s0, bf16* __restrict__ d0,
    const float* __restrict__ s1, bf16* __restrict__ d1,
    const float* __restrict__ s2, bf16* __restrict__ d2,
    const float* __restrict__ s3, bf16* __restrict__ d3,
    const float* __restrict__ s4, bf16* __restrict__ d4,
    const float* __restrict__ s5, bf16* __restrict__ d5,
    const float* __restrict__ lnx, const float* __restrict__ lng,
    const float* __restrict__ lnb, bf16* __restrict__ lnout) {
  int b = blockIdx.x;
  int tx = threadIdx.x, ty = threadIdx.y;  // 32 x 8
  int tid = ty * 32 + tx;
  if (b >= 15360) {  // LayerNorm row -> bf16
    int row = b - 15360;
    float4 v = ((const float4*)(lnx + (long)row * DMODEL))[tid];
    float s = v.x + v.y + v.z + v.w;
    float s2 = v.x * v.x + v.y * v.y + v.z * v.z + v.w * v.w;
#pragma unroll
    for (int off = 32; off > 0; off >>= 1) {
      s += __shfl_down(s, off);
      s2 += __shfl_down(s2, off);
    }
    __shared__ float ss[4], ss2[4];
    int wave = tid >> 6, lane = tid & 63;
    if (lane == 0) { ss[wave] = s; ss2[wave] = s2; }
    __syncthreads();
    s = ss[0] + ss[1] + ss[2] + ss[3];
    s2 = ss2[0] + ss2[1] + ss2[2] + ss2[3];
    float mean = s * (1.0f / DMODEL);
    float var = s2 * (1.0f / DMODEL) - mean * mean;
    float rstd = rsqrtf(var + 1e-5f);
    float4 gg = ((const float4*)lng)[tid];
    float4 bb = ((const float4*)lnb)[tid];
    bf16x4 o{__float2bfloat16((v.x - mean) * rstd * gg.x + bb.x),
             __float2bfloat16((v.y - mean) * rstd * gg.y + bb.y),
             __float2bfloat16((v.z - mean) * rstd * gg.z + bb.z),
             __float2bfloat16((v.w - mean) * rstd * gg.w + bb.w)};
    ((bf16x4*)(lnout + (long)row * DMODEL))[tid] = o;
    return;
  }
  if (b >= 13312) {  // pos cvt
    int idx = (b - 13312) * 256 + tid;
    float4 v = ((const float4*)s5)[idx];
    bf16x4 o{__float2bfloat16(v.x), __float2bfloat16(v.y),
             __float2bfloat16(v.z), __float2bfloat16(v.w)};
    ((bf16x4*)d5)[idx] = o;
    return;
  }
  __shared__ float tile[32][33];
  const float* src; bf16* dst; int R, C, t;
  if (b < 3072)      { src = s0; dst = d0; R = 1024; C = 3072; t = b; }
  else if (b < 4096) { src = s1; dst = d1; R = 1024; C = 1024; t = b - 3072; }
  else if (b < 5120) { src = s2; dst = d2; R = 1024; C = 1024; t = b - 4096; }
  else if (b < 9216) { src = s3; dst = d3; R = 1024; C = 4096; t = b - 5120; }
  else               { src = s4; dst = d4; R = 4096; C = 1024; t = b - 9216; }
  int tcols = C >> 5;
  int bx = (t % tcols) * 32;  // col of src
  int by = (t / tcols) * 32;  // row of src
#pragma unroll
  for (int r = 0; r < 32; r += 8)
    tile[ty + r][tx] = src[(long)(by + ty + r) * C + bx + tx];
  __syncthreads();
#pragma unroll
  for (int r = 0; r < 32; r += 8)
    dst[(long)(bx + ty + r) * R + by + tx] = __float2bfloat16(tile[tx][ty + r]);
}

// ---------------- LayerNorm (D=1024) -> bf16, one block per row ----------------
__global__ __launch_bounds__(256) void ln_cvt(const float* __restrict__ x,
                                              const float* __restrict__ g,
                                              const float* __restrict__ b,
                                              bf16* __restrict__ out) {
  int row = blockIdx.x;
  int tid = threadIdx.x;
  float4 v = ((const float4*)(x + (long)row * DMODEL))[tid];
  float s = v.x + v.y + v.z + v.w;
  float s2 = v.x * v.x + v.y * v.y + v.z * v.z + v.w * v.w;
#pragma unroll
  for (int off = 32; off > 0; off >>= 1) {
    s += __shfl_down(s, off);
    s2 += __shfl_down(s2, off);
  }
  __shared__ float ss[4], ss2[4];
  int wave = tid >> 6, lane = tid & 63;
  if (lane == 0) { ss[wave] = s; ss2[wave] = s2; }
  __syncthreads();
  s = ss[0] + ss[1] + ss[2] + ss[3];
  s2 = ss2[0] + ss2[1] + ss2[2] + ss2[3];
  float mean = s * (1.0f / DMODEL);
  float var = s2 * (1.0f / DMODEL) - mean * mean;
  float rstd = rsqrtf(var + 1e-5f);
  float4 gg = ((const float4*)g)[tid];
  float4 bb = ((const float4*)b)[tid];
  bf16x4 o{__float2bfloat16((v.x - mean) * rstd * gg.x + bb.x),
           __float2bfloat16((v.y - mean) * rstd * gg.y + bb.y),
           __float2bfloat16((v.z - mean) * rstd * gg.z + bb.z),
           __float2bfloat16((v.w - mean) * rstd * gg.w + bb.w)};
  ((bf16x4*)(out + (long)row * DMODEL))[tid] = o;
}

// ---------------- generic MFMA GEMM: C(M,N) = A(M,K) * Bt(N,K)^T ----------------
// 2-phase double-buffered pipeline: per K-step {issue STAGE(next) ->
// ds_read(cur)+MFMA -> one __syncthreads (drains this wave's loads + barrier)}.
template <int BM, int BN, int BK, class Epi>
__global__ __launch_bounds__(256) void gemm_bt(const bf16* __restrict__ A,
                                               const bf16* __restrict__ Bt,
                                               int M, int N, int K,
                                               long aZstride, long bZstride, Epi epi) {
  constexpr int MT = BM / 32;
  constexpr int NT = BN / 32;
  constexpr int KK = BK / 32;
  __shared__ bf16 As[2][BM * BK];
  __shared__ bf16 Bs[2][BN * BK];

  const int bm = blockIdx.y, bn = blockIdx.x, z = blockIdx.z;
  const bf16* Ab = A + (long)z * aZstride + (long)bm * BM * K;
  const bf16* Bb = Bt + (long)z * bZstride + (long)bn * BN * K;

  const int tid = threadIdx.x;
  const int lane = tid & 63;
  const int wave = tid >> 6;
  const int wr = wave >> 1;
  const int wc = wave & 1;
  const int kBeg = epi.kmin(bm, bn, z);
  const int kEnd = epi.kmax(bm, bn, z, K);

  const f32x4 zero4 = {0.f, 0.f, 0.f, 0.f};
  f32x4 acc[MT][NT];
#pragma unroll
  for (int mt = 0; mt < MT; ++mt)
#pragma unroll
    for (int nt = 0; nt < NT; ++nt) acc[mt][nt] = zero4;

  const int aRow = wr * (BM / 2) + (lane & 15);
  const int bRow = wc * (BN / 2) + (lane & 15);
  const int kq = (lane >> 4) * 8;

  // prologue: fill buffer 0
  stage_tile<BM, BK>(Ab + kBeg, K, As[0], tid);
  stage_tile<BN, BK>(Bb + kBeg, K, Bs[0], tid);
  __syncthreads();

  int cur = 0;
  for (int k0 = kBeg; k0 < kEnd; k0 += BK) {
    int kn = k0 + BK;
    if (kn < kEnd) {  // issue next-tile loads; they drain at this step's barrier
      stage_tile<BM, BK>(Ab + kn, K, As[cur ^ 1], tid);
      stage_tile<BN, BK>(Bb + kn, K, Bs[cur ^ 1], tid);
    }
    short8 af[KK][MT], bfr[KK][NT];
#pragma unroll
    for (int kk = 0; kk < KK; ++kk) {
#pragma unroll
      for (int mt = 0; mt < MT; ++mt)
        af[kk][mt] = *(const short8*)(&As[cur][kk * (BM * 32) + (aRow + mt * 16) * 32 + kq]);
#pragma unroll
      for (int nt = 0; nt < NT; ++nt)
        bfr[kk][nt] = *(const short8*)(&Bs[cur][kk * (BN * 32) + (bRow + nt * 16) * 32 + kq]);
    }
#pragma unroll
    for (int kk = 0; kk < KK; ++kk)
#pragma unroll
      for (int mt = 0; mt < MT; ++mt)
#pragma unroll
        for (int nt = 0; nt < NT; ++nt)
          acc[mt][nt] = __builtin_amdgcn_mfma_f32_16x16x32_bf16(af[kk][mt], bfr[kk][nt],
                                                                acc[mt][nt], 0, 0, 0);
    __syncthreads();
    cur ^= 1;
  }

  const int rBase = (lane >> 4) * 4;
  const int cOff = lane & 15;
#pragma unroll
  for (int mt = 0; mt < MT; ++mt) {
#pragma unroll
    for (int nt = 0; nt < NT; ++nt) {
      int row = bm * BM + wr * (BM / 2) + mt * 16 + rBase;
      int col = bn * BN + wc * (BN / 2) + nt * 16 + cOff;
      f32x4 v = acc[mt][nt];
#pragma unroll
      for (int r = 0; r < 4; ++r) epi.store(z, row + r, col, v[r]);
    }
  }
}

// ---------------- epilogues ----------------
struct EpiQKV {
  bf16 *Qh, *Kb, *Vt;
  __device__ int kmin(int, int, int) const { return 0; }
  __device__ int kmax(int, int, int, int K) const { return K; }
  __device__ void store(int, int row, int col, float v) const {
    int n = (col >> 6) & 15, d = col & 63;
    long hoff = ((long)n * T_SEQ + row) * DHEAD + d;
    if (col < DMODEL) {
      Qh[hoff] = __float2bfloat16(v);
    } else if (col < 2 * DMODEL) {
      Kb[hoff] = __float2bfloat16(v);
    } else {
      Vt[((long)n * DHEAD + d) * T_SEQ + row] = __float2bfloat16(v);
    }
  }
};

struct EpiRk {
  bf16* Rk;
  __device__ int kmin(int, int, int) const { return 0; }
  __device__ int kmax(int, int, int, int K) const { return K; }
  __device__ void store(int, int row, int col, float v) const {
    int n = col >> 6, d = col & 63;
    Rk[((long)n * T_SEQ + row) * DHEAD + d] = __float2bfloat16(v);
  }
};

// PV with BM=64: rows [bm*64, bm*64+64) all share kround = ((bm>>1)+1)*128
struct EpiPV {
  bf16* av;
  __device__ int kmin(int, int, int) const { return 0; }
  __device__ int kmax(int bm, int, int, int K) const {
    int kl = ((bm >> 1) + 1) * 128;
    return kl < K ? kl : K;
  }
  __device__ void store(int z, int row, int col, float v) const {
    av[(long)row * DMODEL + z * DHEAD + col] = __float2bfloat16(v);
  }
};

// O-proj epilogue also pre-initializes out = v + input + b2 for FF2's atomics
// (replaces the separate ff2_init kernel).
struct EpiO {
  float* xws;
  const float* inp;
  float* out;
  const float* b2;
  __device__ int kmin(int, int, int) const { return 0; }
  __device__ int kmax(int, int, int, int K) const { return K; }
  __device__ void store(int, int row, int col, float v) const {
    long idx = (long)row * DMODEL + col;
    float t = v + inp[idx];
    xws[idx] = t;
    out[idx] = t + b2[col];
  }
};

struct EpiFF1 {
  bf16* h;
  const float* b1;
  __device__ int kmin(int, int, int) const { return 0; }
  __device__ int kmax(int, int, int, int K) const { return K; }
  __device__ void store(int, int row, int col, float v) const {
    h[(long)row * DFF + col] = __float2bfloat16(fmaxf(v + b1[col], 0.f));
  }
};

// split-K x4: out pre-initialized (EpiO); partials atomic-added (fp32 HW atomic)
struct EpiFF2 {
  float* out;
  __device__ int kmin(int, int, int z) const { return z * 1024; }
  __device__ int kmax(int, int, int z, int K) const {
    int e = z * 1024 + 1024;
    return e < K ? e : K;
  }
  __device__ void store(int, int row, int col, float v) const {
    unsafeAtomicAdd(&out[(long)row * DMODEL + col], v);
  }
};

// ---------------- rank-1 bias rows ----------------
__global__ __launch_bounds__(256) void bias_k(const bf16* __restrict__ Kb,
                                              const bf16* __restrict__ Rk,
                                              const float* __restrict__ rwb,
                                              const float* __restrict__ rrb,
                                              float* __restrict__ acB,
                                              float* __restrict__ rrbR) {
  int idx = blockIdx.x * 256 + threadIdx.x;   // 16*2048
  int n = idx >> 11;
  const short8* kp = (const short8*)(Kb + (long)idx * DHEAD);
  const short8* rp = (const short8*)(Rk + (long)idx * DHEAD);
  float s1 = 0.f, s2 = 0.f;
#pragma unroll
  for (int q8 = 0; q8 < 8; ++q8) {
    short8 kv = kp[q8], rv = rp[q8];
#pragma unroll
    for (int e = 0; e < 8; ++e) {
      float w1 = rwb[n * DHEAD + q8 * 8 + e];
      float w2 = rrb[n * DHEAD + q8 * 8 + e];
      s1 += w1 * __bfloat162float(((const bf16*)&kv)[e]);
      s2 += w2 * __bfloat162float(((const bf16*)&rv)[e]);
    }
  }
  acB[idx] = s1;
  rrbR[idx] = s2;
}

// ---------------- fused score kernel (round-1 version, verbatim) ----------------
__global__ __launch_bounds__(256) void score_k(const bf16* __restrict__ Qh,
                                               const bf16* __restrict__ Kb,
                                               const bf16* __restrict__ Rk,
                                               const float* __restrict__ acB,
                                               const float* __restrict__ rrbR,
                                               bf16* __restrict__ score) {
  const int bn = blockIdx.x, bm = blockIdx.y, z = blockIdx.z;
  if (bn > bm) return;
  __shared__ char smem[70656];               // max(staging 64KB, 2*64*276*2)
  bf16* Qs  = (bf16*)smem;             // 128x64, two 32-wide K panels (16 KB)
  bf16* Ks  = (bf16*)(smem + 16384);   // 128x64 (16 KB)
  bf16* Bnd = (bf16*)(smem + 32768);   // 256x64 (32 KB)

  const int tid = threadIdx.x;
  const int lane = tid & 63, wave = tid >> 6;
  const int wr = wave >> 1, wc = wave & 1;
  const int kq = (lane >> 4) * 8;
  const int l15 = lane & 15;
  const int base = 128 * (bn - bm) + T_SEQ - 1 - 128;

  const bf16* Qg = Qh + ((long)z * T_SEQ + bm * 128) * DHEAD;
  const bf16* Kg = Kb + ((long)z * T_SEQ + bn * 128) * DHEAD;
  const bf16* Rg = Rk + (long)z * T_SEQ * DHEAD;

#pragma unroll
  for (int it = 0; it < 4; ++it) {
    int s = it * 256 + tid;
    int kh = s >> 9, r = (s >> 2) & 127, c = (s & 3) * 8;
    async_cp16(Qg + (long)r * DHEAD + kh * 32 + c, Qs + s * 8);
    async_cp16(Kg + (long)r * DHEAD + kh * 32 + c, Ks + s * 8);
  }
#pragma unroll
  for (int it = 0; it < 8; ++it) {
    int s = it * 256 + tid;
    int kh = s >> 10, u = (s >> 2) & 255, c = (s & 3) * 8;
    int g = base + u;
    g = g < 0 ? 0 : (g > T_SEQ - 1 ? T_SEQ - 1 : g);
    async_cp16(Rg + (long)g * DHEAD + kh * 32 + c, Bnd + s * 8);
  }

  const f32x4 zero4 = {0.f, 0.f, 0.f, 0.f};
  f32x4 accA[4][4], accW[4][8];
#pragma unroll
  for (int mt = 0; mt < 4; ++mt) {
#pragma unroll
    for (int nt = 0; nt < 4; ++nt) accA[mt][nt] = zero4;
#pragma unroll
    for (int ut = 0; ut < 8; ++ut) accW[mt][ut] = zero4;
  }

  __syncthreads();
#pragma unroll
  for (int kh = 0; kh < 2; ++kh) {
    short8 qa[4], kf[4], wf[8];
#pragma unroll
    for (int mt = 0; mt < 4; ++mt)
      qa[mt] = *(const short8*)(Qs + kh * 4096 + (wr * 64 + mt * 16 + l15) * 32 + kq);
#pragma unroll
    for (int nt = 0; nt < 4; ++nt)
      kf[nt] = *(const short8*)(Ks + kh * 4096 + (wc * 64 + nt * 16 + l15) * 32 + kq);
#pragma unroll
    for (int ut = 0; ut < 8; ++ut)
      wf[ut] = *(const short8*)(Bnd + kh * 8192 + (wc * 128 + ut * 16 + l15) * 32 + kq);
#pragma unroll
    for (int mt = 0; mt < 4; ++mt) {
#pragma unroll
      for (int nt = 0; nt < 4; ++nt)
        accA[mt][nt] = __builtin_amdgcn_mfma_f32_16x16x32_bf16(qa[mt], kf[nt], accA[mt][nt], 0, 0, 0);
#pragma unroll
      for (int ut = 0; ut < 8; ++ut)
        accW[mt][ut] = __builtin_amdgcn_mfma_f32_16x16x32_bf16(qa[mt], wf[ut], accW[mt][ut], 0, 0, 0);
    }
  }

  float wbias[8];
#pragma unroll
  for (int ut = 0; ut < 8; ++ut) {
    int u = wc * 128 + ut * 16 + l15;
    int g = base + u;
    g = g < 0 ? 0 : (g > T_SEQ - 1 ? T_SEQ - 1 : g);
    wbias[ut] = rrbR[(long)z * T_SEQ + g];
  }
  float abias[4];
#pragma unroll
  for (int nt = 0; nt < 4; ++nt)
    abias[nt] = acB[(long)z * T_SEQ + bn * 128 + wc * 64 + nt * 16 + l15];

  __syncthreads();  // all frag reads done; smem reusable

  bf16* Wl = (bf16*)smem + wr * (64 * 276);
  const int quad4 = (lane >> 4) * 4;
  const int umin = wr ? 1 : 65;    // u range actually read back for this half
  const int umax = wr ? 191 : 255;
#pragma unroll
  for (int mt = 0; mt < 4; ++mt) {
#pragma unroll
    for (int ut = 0; ut < 8; ++ut) {
      int ub = wc * 128 + ut * 16;
      if (ub + 15 < umin || ub > umax) continue;
      int lr = mt * 16 + quad4;
      int u = ub + l15;
#pragma unroll
      for (int reg = 0; reg < 4; ++reg)
        Wl[(lr + reg) * 276 + u] = __float2bfloat16(accW[mt][ut][reg] + wbias[ut]);
    }
  }
  __syncthreads();

  bf16* srow = score + (long)z * T_SEQ * T_SEQ;
#pragma unroll
  for (int mt = 0; mt < 4; ++mt) {
#pragma unroll
    for (int nt = 0; nt < 4; ++nt) {
      int lr = mt * 16 + quad4;
      int c = wc * 64 + nt * 16 + l15;
#pragma unroll
      for (int reg = 0; reg < 4; ++reg) {
        int rl = lr + reg;
        int r = wr * 64 + rl;
        int u = c - r + 128;
        float v = accA[mt][nt][reg] + abias[nt] +
                  __bfloat162float(Wl[rl * 276 + u]);
        srow[(long)(bm * 128 + r) * T_SEQ + bn * 128 + c] = __float2bfloat16(v);
      }
    }
  }
}

// ---------------- softmax: block per row i; 16 waves, wave h owns head h ----------------
__global__ __launch_bounds__(1024) void softmax_k(const bf16* __restrict__ S,
                                                  float* __restrict__ probs,
                                                  bf16* __restrict__ pb) {
  constexpr int HS = T_SEQ + 8;            // LDS head stride (bf16), 16B pad
  __shared__ bf16 pl[NHEAD * HS];          // ~65.8 KB
  __shared__ float rinv_s[NHEAD];
  const int i = blockIdx.x;
  const int tid = threadIdx.x;
  const int h = tid >> 6, lane = tid & 63;
  const float scale = 0.125f;              // 1/sqrt(64)
  const int nch = (i >> 9) + 1;            // 512-wide chunks covering the row

  const bf16* row = S + (long)h * T_SEQ * T_SEQ + (long)i * T_SEQ;

  short8 v[4];
  float m = -1e30f;
#pragma unroll
  for (int c = 0; c < 4; ++c) {
    if (c < nch) {
      int j0 = c * 512 + lane * 8;
      v[c] = *(const short8*)(row + j0);
#pragma unroll
      for (int e = 0; e < 8; ++e) {
        float s = (j0 + e <= i) ? __bfloat162float(((const bf16*)&v[c])[e]) * scale : -1e30f;
        m = fmaxf(m, s);
      }
    }
  }
#pragma unroll
  for (int off = 1; off < 64; off <<= 1) m = fmaxf(m, __shfl_xor(m, off));

  float l = 0.f;
#pragma unroll
  for (int c = 0; c < 4; ++c) {
    if (c < nch) {
      int j0 = c * 512 + lane * 8;
      short8 o;
#pragma unroll
      for (int e = 0; e < 8; ++e) {
        float p = 0.f;
        if (j0 + e <= i) {
          p = __expf(__bfloat162float(((const bf16*)&v[c])[e]) * scale - m);
          l += p;
        }
        ((bf16*)&o)[e] = __float2bfloat16(p);
      }
      *(short8*)(pl + h * HS + j0) = o;
    }
  }
#pragma unroll
  for (int off = 1; off < 64; off <<= 1) l += __shfl_xor(l, off);
  if (lane == 0) rinv_s[h] = 1.f / l;
  __syncthreads();

  float* prow = probs + (long)i * T_SEQ * NHEAD;
  const int n0 = (tid & 3) * 4;
  const float rv0 = rinv_s[n0 + 0], rv1 = rinv_s[n0 + 1];
  const float rv2 = rinv_s[n0 + 2], rv3 = rinv_s[n0 + 3];
#pragma unroll
  for (int it = 0; it < 8; ++it) {
    int o = it * 1024 + tid;
    int j = o >> 2;
    float4 f = {0.f, 0.f, 0.f, 0.f};
    if (j <= i) {
      f.x = __bfloat162float(pl[(n0 + 0) * HS + j]) * rv0;
      f.y = __bfloat162float(pl[(n0 + 1) * HS + j]) * rv1;
      f.z = __bfloat162float(pl[(n0 + 2) * HS + j]) * rv2;
      f.w = __bfloat162float(pl[(n0 + 3) * HS + j]) * rv3;
    }
    ((float4*)prow)[o] = f;
  }

  const int kround = ((i >> 7) + 1) << 7;
  bf16* prow_b = pb + (long)h * T_SEQ * T_SEQ + (long)i * T_SEQ;
  const float rinv = rinv_s[h];
  for (int j0 = lane * 8; j0 < kround; j0 += 512) {
    short8 pv = *(const short8*)(pl + h * HS + j0);
    short8 o;
#pragma unroll
    for (int e = 0; e < 8; ++e)
      ((bf16*)&o)[e] = __float2bfloat16(__bfloat162float(((const bf16*)&pv)[e]) * rinv);
    *(short8*)(prow_b + j0) = o;
  }
}

// ---------------- host launch ----------------
extern "C" void kernel_launch(void* const* d_in, const int* in_sizes, int n_in,
                              void* d_out, int out_size, void* d_ws, size_t ws_size,
                              hipStream_t stream) {
  const float* input = (const float*)d_in[0];
  const float* pos   = (const float*)d_in[1];
  const float* rwb   = (const float*)d_in[2];
  const float* rrb   = (const float*)d_in[3];
  // d_in[4] = mask (causal, recomputed analytically)
  const float* ln1g  = (const float*)d_in[5];
  const float* ln1b  = (const float*)d_in[6];
  const float* qkvw  = (const float*)d_in[7];
  const float* rw    = (const float*)d_in[8];
  const float* ow    = (const float*)d_in[9];
  const float* ln2g  = (const float*)d_in[10];
  const float* ln2b  = (const float*)d_in[11];
  const float* ffw1  = (const float*)d_in[12];
  const float* ffb1  = (const float*)d_in[13];
  const float* ffw2  = (const float*)d_in[14];
  const float* ffb2  = (const float*)d_in[15];
  float* out = (float*)d_out;  // [0, 2M): x   [2M, 2M+67M): probs

  size_t off = 0;
  auto alloc = [&](size_t bytes) -> char* {
    char* p = (char*)d_ws + off;
    off += (bytes + 255) & ~(size_t)255;
    return p;
  };
  bf16* wqkvT = (bf16*)alloc(3072L * 1024 * 2);
  bf16* wrT   = (bf16*)alloc(1024L * 1024 * 2);
  bf16* woT   = (bf16*)alloc(1024L * 1024 * 2);
  bf16* wf1T  = (bf16*)alloc(4096L * 1024 * 2);
  bf16* wf2T  = (bf16*)alloc(1024L * 4096 * 2);
  bf16* qin   = (bf16*)alloc(2048L * 1024 * 2);
  bf16* posb  = (bf16*)alloc(2048L * 1024 * 2);
  bf16* Qh    = (bf16*)alloc(16L * 2048 * 64 * 2);
  bf16* Kb    = (bf16*)alloc(16L * 2048 * 64 * 2);
  bf16* Vt    = (bf16*)alloc(16L * 64 * 2048 * 2);
  bf16* Rk    = (bf16*)alloc(16L * 2048 * 64 * 2);
  float* acB  = (float*)alloc(16L * 2048 * 4);
  float* rrbR = (float*)alloc(16L * 2048 * 4);
  bf16* ACb   = (bf16*)alloc(16L * 2048 * 2048 * 2);  // 134 MB score
  bf16* pb    = (bf16*)alloc(16L * 2048 * 2048 * 2);  // 134 MB probs bf16
  bf16* av    = (bf16*)alloc(2048L * 1024 * 2);
  float* xws  = (float*)alloc(2048L * 1024 * 4);
  bf16* yb    = (bf16*)alloc(2048L * 1024 * 2);
  bf16* hb    = (bf16*)alloc(2048L * 4096 * 2);

  dim3 tb(32, 8);
  transpose_all<<<17408, tb, 0, stream>>>(qkvw, wqkvT, rw, wrT, ow, woT,
                                          ffw1, wf1T, ffw2, wf2T, pos, posb,
                                          input, ln1g, ln1b, qin);

  {
    EpiQKV e{Qh, Kb, Vt};
    gemm_bt<128, 64, 64, EpiQKV><<<dim3(48, 16, 1), 256, 0, stream>>>(qin, wqkvT, 2048, 3072, 1024, 0, 0, e);
  }
  {
    EpiRk e{Rk};
    gemm_bt<64, 64, 64, EpiRk><<<dim3(16, 32, 1), 256, 0, stream>>>(posb, wrT, 2048, 1024, 1024, 0, 0, e);
  }
  bias_k<<<128, 256, 0, stream>>>(Kb, Rk, rwb, rrb, acB, rrbR);
  score_k<<<dim3(16, 16, 16), 256, 0, stream>>>(Qh, Kb, Rk, acB, rrbR, ACb);
  softmax_k<<<2048, 1024, 0, stream>>>(ACb, out + 2048L * 1024, pb);
  {
    EpiPV e{av};
    gemm_bt<64, 64, 64, EpiPV><<<dim3(1, 32, 16), 256, 0, stream>>>(pb, Vt, 2048, 64, 2048,
                                                                    2048L * 2048, 64L * 2048, e);
  }
  {
    EpiO e{xws, input, out, ffb2};
    gemm_bt<64, 64, 64, EpiO><<<dim3(16, 32, 1), 256, 0, stream>>>(av, woT, 2048, 1024, 1024, 0, 0, e);
  }
  ln_cvt<<<2048, 256, 0, stream>>>(xws, ln2g, ln2b, yb);
  {
    EpiFF1 e{hb, ffb1};
    gemm_bt<128, 64, 64, EpiFF1><<<dim3(64, 16, 1), 256, 0, stream>>>(yb, wf1T, 2048, 4096, 1024, 0, 0, e);
  }
  {
    EpiFF2 e{out};
    gemm_bt<128, 64, 64, EpiFF2><<<dim3(16, 16, 4), 256, 0, stream>>>(hb, wf2T, 2048, 1024, 4096, 0, 0, e);
  }
}